// Round 12
// baseline (413.781 us; speedup 1.0000x reference)
//
#include <hip/hip_runtime.h>
#include <math.h>

#define BB    256      // batch
#define DIN   512
#define HD    512
#define DOUT  10
#define NS    32       // samples
#define NIDX  2560     // BB*DOUT
#define MAXIT 10
#define CG_EPS 1e-12f

typedef __attribute__((ext_vector_type(8))) short s16x8;   // 8 bf16 (4 VGPRs)
typedef __attribute__((ext_vector_type(4))) float f32x4;   // 4 fp32 acc

// ---------------- helpers ----------------
__device__ __forceinline__ float wave_red(float v){
  #pragma unroll
  for (int off = 32; off > 0; off >>= 1) v += __shfl_down(v, off, 64);
  return v;  // lane 0 holds total
}
__device__ __forceinline__ unsigned short f2bf(float f){
  unsigned u = __float_as_uint(f);
  return (unsigned short)((u + 0x7FFFu + ((u >> 16) & 1u)) >> 16);
}
__device__ __forceinline__ float bf2f(unsigned short h){
  return __uint_as_float((unsigned)h << 16);
}

typedef const __attribute__((address_space(1))) unsigned short gus_t;
typedef __attribute__((address_space(3))) unsigned short lus_t;
__device__ __forceinline__ void gload16(const unsigned short* g, unsigned short* l){
  // async global->LDS, 16B/lane; LDS dest = wave-uniform base + lane*16
  __builtin_amdgcn_global_load_lds((gus_t*)g, (lus_t*)l, 16, 0, 0);
}

// ---------------- forward: h, G ----------------
__global__ __launch_bounds__(256) void k_gemm_z(
    const float* __restrict__ x, const float* __restrict__ W1,
    const float* __restrict__ b1, float* __restrict__ h, float* __restrict__ G)
{
  __shared__ __align__(16) float Al[16][68];
  __shared__ __align__(16) float Bl[16][64];
  const int tid = threadIdx.x;
  const int m0 = blockIdx.y * 64, n0 = blockIdx.x * 64;
  const int tx = tid & 15, ty = tid >> 4;
  float acc[4][4] = {};
  for (int k0 = 0; k0 < DIN; k0 += 16){
    {
      int m = tid >> 2, kk = (tid & 3) << 2;
      float4 a = *(const float4*)(x + (size_t)(m0+m)*DIN + k0 + kk);
      Al[kk+0][m]=a.x; Al[kk+1][m]=a.y; Al[kk+2][m]=a.z; Al[kk+3][m]=a.w;
    }
    {
      int kk = tid >> 4, n = (tid & 15) << 2;
      *(float4*)&Bl[kk][n] = *(const float4*)(W1 + (size_t)(k0+kk)*HD + n0 + n);
    }
    __syncthreads();
    #pragma unroll
    for (int kk = 0; kk < 16; kk++){
      float4 av = *(const float4*)&Al[kk][ty<<2];
      float4 bv = *(const float4*)&Bl[kk][tx<<2];
      float aa[4]={av.x,av.y,av.z,av.w}, bb[4]={bv.x,bv.y,bv.z,bv.w};
      #pragma unroll
      for (int i=0;i<4;i++)
        #pragma unroll
        for (int j=0;j<4;j++) acc[i][j] += aa[i]*bb[j];
    }
    __syncthreads();
  }
  float4 b4 = *(const float4*)&b1[n0 + (tx<<2)];
  float bbv[4] = {b4.x,b4.y,b4.z,b4.w};
  #pragma unroll
  for (int i=0;i<4;i++){
    int m = m0 + (ty<<2) + i;
    float hh[4], gg[4];
    #pragma unroll
    for (int j=0;j<4;j++){ float t = tanhf(acc[i][j] + bbv[j]); hh[j]=t; gg[j]=1.0f-t*t; }
    *(float4*)&h[(size_t)m*HD + n0 + (tx<<2)] = make_float4(hh[0],hh[1],hh[2],hh[3]);
    *(float4*)&G[(size_t)m*HD + n0 + (tx<<2)] = make_float4(gg[0],gg[1],gg[2],gg[3]);
  }
}

// ---------------- Kx = x x^T + 1 ; Kh = h h^T + 1 ----------------
__global__ __launch_bounds__(256) void k_gemm_kxkh(
    const float* __restrict__ x, const float* __restrict__ h,
    float* __restrict__ Kx, float* __restrict__ Kh)
{
  __shared__ __align__(16) float Al[16][68];
  __shared__ __align__(16) float Bl[16][68];
  const int tid = threadIdx.x;
  const float* A = blockIdx.z ? h : x;
  float* C = blockIdx.z ? Kh : Kx;
  const int m0 = blockIdx.y * 64, n0 = blockIdx.x * 64;
  const int tx = tid & 15, ty = tid >> 4;
  float acc[4][4] = {};
  for (int k0 = 0; k0 < DIN; k0 += 16){
    {
      int m = tid >> 2, kk = (tid & 3) << 2;
      float4 a = *(const float4*)(A + (size_t)(m0+m)*DIN + k0 + kk);
      Al[kk+0][m]=a.x; Al[kk+1][m]=a.y; Al[kk+2][m]=a.z; Al[kk+3][m]=a.w;
      float4 b = *(const float4*)(A + (size_t)(n0+m)*DIN + k0 + kk);
      Bl[kk+0][m]=b.x; Bl[kk+1][m]=b.y; Bl[kk+2][m]=b.z; Bl[kk+3][m]=b.w;
    }
    __syncthreads();
    #pragma unroll
    for (int kk = 0; kk < 16; kk++){
      float4 av = *(const float4*)&Al[kk][ty<<2];
      float4 bv = *(const float4*)&Bl[kk][tx<<2];
      float aa[4]={av.x,av.y,av.z,av.w}, bb[4]={bv.x,bv.y,bv.z,bv.w};
      #pragma unroll
      for (int i=0;i<4;i++)
        #pragma unroll
        for (int j=0;j<4;j++) acc[i][j] += aa[i]*bb[j];
    }
    __syncthreads();
  }
  #pragma unroll
  for (int i=0;i<4;i++){
    int m = m0 + (ty<<2) + i;
    *(float4*)&C[(size_t)m*BB + n0 + (tx<<2)] =
        make_float4(acc[i][0]+1.0f, acc[i][1]+1.0f, acc[i][2]+1.0f, acc[i][3]+1.0f);
  }
}

// ---------------- E2 = [Ehi | Elo] bf16, E[(b,o)][j] = G[b][j]*W2[j][o] ----------------
__global__ __launch_bounds__(256) void k_buildE(
    const float* __restrict__ G, const float* __restrict__ W2,
    unsigned short* __restrict__ E2)
{
  int gid = blockIdx.x * 256 + threadIdx.x;   // 2560 rows * 128 j4-chunks
  int row = gid >> 7, j4 = (gid & 127) << 2;
  int b = row / 10, o = row - b * 10;
  float4 g = *(const float4*)&G[(size_t)b*HD + j4];
  float e[4] = { g.x * W2[(j4+0)*DOUT + o], g.y * W2[(j4+1)*DOUT + o],
                 g.z * W2[(j4+2)*DOUT + o], g.w * W2[(j4+3)*DOUT + o] };
  unsigned short hi[4], lo[4];
  #pragma unroll
  for (int r = 0; r < 4; r++){
    hi[r] = f2bf(e[r]);
    lo[r] = f2bf(e[r] - bf2f(hi[r]));
  }
  *(ushort4*)&E2[(size_t)row*1024 + j4]       = make_ushort4(hi[0],hi[1],hi[2],hi[3]);
  *(ushort4*)&E2[(size_t)row*1024 + 512 + j4] = make_ushort4(lo[0],lo[1],lo[2],lo[3]);
}

// ---------------- x2 = [xhi | xlo] bf16 ----------------
__global__ __launch_bounds__(256) void k_prepx(
    const float* __restrict__ x, unsigned short* __restrict__ x2)
{
  int gid = blockIdx.x * 256 + threadIdx.x;   // 256 rows * 128 j4-chunks
  int row = gid >> 7, j4 = (gid & 127) << 2;
  float4 v = *(const float4*)&x[(size_t)row*DIN + j4];
  float e[4] = {v.x, v.y, v.z, v.w};
  unsigned short hi[4], lo[4];
  #pragma unroll
  for (int r = 0; r < 4; r++){
    hi[r] = f2bf(e[r]);
    lo[r] = f2bf(e[r] - bf2f(hi[r]));
  }
  *(ushort4*)&x2[(size_t)row*1024 + j4]       = make_ushort4(hi[0],hi[1],hi[2],hi[3]);
  *(ushort4*)&x2[(size_t)row*1024 + 512 + j4] = make_ushort4(lo[0],lo[1],lo[2],lo[3]);
}

// ---------------- M2 = split-bf16 of (Kx .* (E E^T) + delta_{oo'} Kh) ----------------
// LDS-staged MFMA GEMM, BK=128. Tile 128m x 64n, grid (40 n, 20 m), 128 thr (2 waves).
// 12 K-steps over 3 phases (hi*hi, hi*lo, lo*hi) x 4 steps of 128 cols. Staging via
// global_load_lds w=16 with XOR-swizzled source chunks (T2; rule #21). MAC order
// identical to BK=64 version (same k sequence) -> bitwise-identical output.
__global__ __launch_bounds__(128) void k_gemm_M(
    const unsigned short* __restrict__ E2, const float* __restrict__ Kx,
    const float* __restrict__ Kh, unsigned short* __restrict__ M2)
{
  __shared__ __align__(16) unsigned short As[128*128];   // 32 KB, row stride 128
  __shared__ __align__(16) unsigned short Bs[64*128];    // 16 KB
  const int tid = threadIdx.x;
  const int w = tid >> 6, l = tid & 63;
  const int ln = l & 15, kq = l >> 4;
  const int m0 = blockIdx.y << 7, n0 = blockIdx.x << 6;

  // staging: per call, thread handles row srow (8 rows/call across 2 waves),
  // col-chunk cc in [0,16); source chunk = (cc&8) | ((cc&7) ^ (row&7))
  const int srow = tid >> 4;                 // 0..7
  const int cc   = tid & 15;
  const int scc  = (cc & 8) | ((cc & 7) ^ (srow & 7));
  const unsigned short* gA = E2 + (size_t)(m0 + srow)*1024 + scc*8;
  const unsigned short* gB = E2 + (size_t)(n0 + srow)*1024 + scc*8;
  unsigned short* lA = As + ((tid & 64) << 3);   // wave-uniform base
  unsigned short* lB = Bs + ((tid & 64) << 3);

  f32x4 acc[4][4];
  #pragma unroll
  for (int i = 0; i < 4; i++)
    #pragma unroll
    for (int j = 0; j < 4; j++)
      acc[i][j] = (f32x4){0.f, 0.f, 0.f, 0.f};

  const int xs = ln & 7;   // read-side swizzle key (frag row & 7 == ln & 7)

  for (int t = 0; t < 12; ++t){
    const int p = t >> 2, k8 = t & 3;
    const int oa = ((p == 2) ? 512 : 0) + (k8 << 7);
    const int ob = ((p == 1) ? 512 : 0) + (k8 << 7);
    #pragma unroll
    for (int c = 0; c < 16; c++)
      gload16(gA + (size_t)c*8*1024 + oa, lA + c*1024);
    #pragma unroll
    for (int c = 0; c < 8; c++)
      gload16(gB + (size_t)c*8*1024 + ob, lB + c*1024);
    __syncthreads();   // drains vmcnt (gload_lds) before LDS reads

    #pragma unroll
    for (int kk = 0; kk < 4; kk++){
      const int kc = kq + (kk << 2);          // 8-elem chunk index 0..15
      const int co = ((kc & 8) | ((kc & 7) ^ xs)) << 3;
      s16x8 af[4], bf[4];
      #pragma unroll
      for (int f = 0; f < 4; f++){
        af[f] = *(const s16x8*)(As + ((w<<6) + (f<<4) + ln)*128 + co);
        bf[f] = *(const s16x8*)(Bs + ((f<<4) + ln)*128 + co);
      }
      #pragma unroll
      for (int fi = 0; fi < 4; fi++)
        #pragma unroll
        for (int fj = 0; fj < 4; fj++)
          acc[fi][fj] = __builtin_amdgcn_mfma_f32_16x16x32_bf16(
              af[fi], bf[fj], acc[fi][fj], 0, 0, 0);
    }
    __syncthreads();   // LDS reuse next step
  }

  // epilogue: v = Kx*acc (+ Kh on o-diagonal); split-bf16 write, coalesced rows
  const int mb = m0 + (w << 6);
  int bmv[4][4], omv[4][4], bnv[4], onv[4];
  #pragma unroll
  for (int f = 0; f < 4; f++){
    int n = n0 + f*16 + ln; bnv[f] = n / 10; onv[f] = n - bnv[f]*10;
    #pragma unroll
    for (int r = 0; r < 4; r++){
      int m = mb + f*16 + kq*4 + r;
      bmv[f][r] = m / 10; omv[f][r] = m - bmv[f][r]*10;
    }
  }
  #pragma unroll
  for (int fi = 0; fi < 4; fi++)
    #pragma unroll
    for (int r = 0; r < 4; r++){
      const int m = mb + fi*16 + kq*4 + r;
      #pragma unroll
      for (int fj = 0; fj < 4; fj++){
        const int n = n0 + fj*16 + ln;
        float v = Kx[(size_t)bmv[fi][r]*BB + bnv[fj]] * acc[fi][fj][r];
        if (omv[fi][r] == onv[fj]) v += Kh[(size_t)bmv[fi][r]*BB + bnv[fj]];
        unsigned short hv = f2bf(v);
        M2[(size_t)m*5120 + n]        = hv;
        M2[(size_t)m*5120 + 2560 + n] = f2bf(v - bf2f(hv));
      }
    }
}

// ---------------- T[s] = (x @ eps_W1[s] + eps_b1[s]) * G  via split-bf16 MFMA ----------------
// grid (8 n-tiles, 32 samples) x 512 thr (8 waves). Wave w owns m-frags {2w, 2w+1}.
__global__ __launch_bounds__(512) void k_gemm_T(
    const unsigned short* __restrict__ x2, const float* __restrict__ eW1,
    const float* __restrict__ eb1, const float* __restrict__ G,
    float* __restrict__ T)
{
  const int tid = threadIdx.x;
  const int w = tid >> 6, l = tid & 63;
  const int ln = l & 15, kq = l >> 4;
  const int n0 = blockIdx.x << 6;
  const int s  = blockIdx.y;
  const float* Wb = eW1 + (size_t)s * DIN * HD;

  const unsigned short* pa[2];
  #pragma unroll
  for (int f = 0; f < 2; f++)
    pa[f] = x2 + (size_t)(16*(2*w + f) + ln) * 1024 + kq * 8;

  f32x4 acc[2][4];
  #pragma unroll
  for (int i = 0; i < 2; i++)
    #pragma unroll
    for (int j = 0; j < 4; j++)
      acc[i][j] = (f32x4){0.f, 0.f, 0.f, 0.f};

  #pragma unroll 2
  for (int k0 = 0; k0 < DIN; k0 += 32){
    float wv[4][8];
    const float* wp = Wb + (size_t)(k0 + kq*8)*HD + n0 + ln;
    #pragma unroll
    for (int i = 0; i < 8; i++)
      #pragma unroll
      for (int f = 0; f < 4; f++)
        wv[f][i] = wp[(size_t)i*HD + 16*f];

    s16x8 ahi[2], alo[2], bhi[4], blo[4];
    #pragma unroll
    for (int f = 0; f < 2; f++){
      ahi[f] = *(const s16x8*)(pa[f] + k0);
      alo[f] = *(const s16x8*)(pa[f] + 512 + k0);
    }
    #pragma unroll
    for (int f = 0; f < 4; f++)
      #pragma unroll
      for (int i = 0; i < 8; i++){
        unsigned short hh = f2bf(wv[f][i]);
        bhi[f][i] = (short)hh;
        blo[f][i] = (short)f2bf(wv[f][i] - bf2f(hh));
      }
    #pragma unroll
    for (int fi = 0; fi < 2; fi++)
      #pragma unroll
      for (int fj = 0; fj < 4; fj++){
        acc[fi][fj] = __builtin_amdgcn_mfma_f32_16x16x32_bf16(ahi[fi], bhi[fj], acc[fi][fj], 0,0,0);
        acc[fi][fj] = __builtin_amdgcn_mfma_f32_16x16x32_bf16(ahi[fi], blo[fj], acc[fi][fj], 0,0,0);
        acc[fi][fj] = __builtin_amdgcn_mfma_f32_16x16x32_bf16(alo[fi], bhi[fj], acc[fi][fj], 0,0,0);
      }
  }

  #pragma unroll
  for (int fj = 0; fj < 4; fj++){
    const int n = n0 + 16*fj + ln;
    const float eb = eb1[(size_t)s*HD + n];
    #pragma unroll
    for (int fi = 0; fi < 2; fi++)
      #pragma unroll
      for (int q = 0; q < 4; q++){
        const int m = 16*(2*w + fi) + kq*4 + q;
        T[((size_t)s*BB + m)*HD + n] = (acc[fi][fj][q] + eb) * G[(size_t)m*HD + n];
      }
  }
}

// ---------------- bvec (+ out0 for s==0 blocks) ----------------
__global__ __launch_bounds__(256) void k_bvec(
    const float* __restrict__ T, const float* __restrict__ W2,
    const float* __restrict__ h, const float* __restrict__ eW2,
    const float* __restrict__ eb2, const float* __restrict__ b2,
    float* __restrict__ bvec, float* __restrict__ out0, float* __restrict__ rr0_part)
{
  __shared__ __align__(16) float W2t[10][516];
  __shared__ __align__(16) float E2t[10][516];
  __shared__ float wl[4];
  const int tid = threadIdx.x, bid = blockIdx.x;
  const int s = bid / 10;
  const int idx = (bid % 10) * 256 + tid;
  const int b = idx / 10, o = idx - b*10;
  const float* e2 = eW2 + (size_t)s * HD * DOUT;
  for (int i = tid; i < HD*DOUT; i += 256){
    int k = i / 10, oo = i - k*10;
    W2t[oo][k] = W2[i];
    E2t[oo][k] = e2[i];
  }
  __syncthreads();
  const float* Tr = T + ((size_t)s*BB + b) * HD;
  const float* hr = h + (size_t)b * HD;
  const bool do0 = (bid < 10);
  float acc = eb2[s*DOUT + o];
  float a0 = 0.f;
  #pragma unroll 4
  for (int k4 = 0; k4 < HD/4; k4++){
    float4 t4 = *(const float4*)(Tr + (k4<<2));
    float4 h4 = *(const float4*)(hr + (k4<<2));
    float4 w4 = *(const float4*)&W2t[o][k4<<2];
    float4 q4 = *(const float4*)&E2t[o][k4<<2];
    acc += t4.x*w4.x + t4.y*w4.y + t4.z*w4.z + t4.w*w4.w
         + h4.x*q4.x + h4.y*q4.y + h4.z*q4.z + h4.w*q4.w;
    if (do0) a0 += h4.x*w4.x + h4.y*w4.y + h4.z*w4.z + h4.w*w4.w;
  }
  bvec[(size_t)s*NIDX + idx] = acc;
  if (do0) out0[idx] = a0 + b2[o];
  float v = wave_red(acc * acc);
  if ((tid & 63) == 0) wl[tid >> 6] = v;
  __syncthreads();
  if (tid == 0) rr0_part[bid] = wl[0]+wl[1]+wl[2]+wl[3];
}

// ---------------- CG init ----------------
__global__ __launch_bounds__(256) void k_init(
    const float* __restrict__ bvec, const float* __restrict__ rr0_part,
    float* __restrict__ r, float* __restrict__ p, float* __restrict__ a,
    float* __restrict__ basis, float* __restrict__ rr_arr,
    unsigned short* __restrict__ ps2)
{
  int gid = blockIdx.x * 256 + threadIdx.x;
  int s = gid / NIDX, idx = gid - s * NIDX;
  float rr0 = 0.f;
  #pragma unroll
  for (int i = 0; i < 10; i++) rr0 += rr0_part[s*10 + i];
  float bv = bvec[gid];
  r[gid] = bv; p[gid] = bv; a[gid] = 0.f;
  basis[gid] = bv / (sqrtf(rr0) + CG_EPS);
  unsigned short hh = f2bf(bv);
  ps2[(size_t)s*5120 + idx]        = hh;
  ps2[(size_t)s*5120 + 2560 + idx] = f2bf(bv - bf2f(hh));
  if (threadIdx.x == 0) rr_arr[s] = rr0;
}

// ---------------- matvec: Ap_part[kh][s][r] via split-bf16 MFMA ----------------
// grid (160 row-blocks of 16, 4 K-quarters), 256 thr (4 waves, wave = 160-col slice).
__global__ __launch_bounds__(256) void k_matvec(
    const unsigned short* __restrict__ M2, const unsigned short* __restrict__ p2,
    float* __restrict__ Ap_part)
{
  __shared__ float red[4][16][33];
  const int tid = threadIdx.x;
  const int w = tid >> 6, l = tid & 63;
  const int ln = l & 15, kq = l >> 4;
  const int R0 = blockIdx.x << 4;
  const int kh = blockIdx.y;                 // 0..3
  const int c0 = kh*640 + w*160;

  const unsigned short* a0p = M2 + (size_t)(R0 + ln)*5120 + c0 + kq*8;
  const unsigned short* q0  = p2 + (size_t)ln*5120        + c0 + kq*8;
  const unsigned short* q1  = p2 + (size_t)(16 + ln)*5120 + c0 + kq*8;

  f32x4 acc[2];
  acc[0] = (f32x4){0.f,0.f,0.f,0.f};
  acc[1] = (f32x4){0.f,0.f,0.f,0.f};

  #pragma unroll
  for (int ch = 0; ch < 5; ch++){
    const int o = ch * 32;
    s16x8 bh0 = *(const s16x8*)(q0 + o);
    s16x8 bl0 = *(const s16x8*)(q0 + 2560 + o);
    s16x8 bh1 = *(const s16x8*)(q1 + o);
    s16x8 bl1 = *(const s16x8*)(q1 + 2560 + o);
    s16x8 a0h = *(const s16x8*)(a0p + o);
    s16x8 a0l = *(const s16x8*)(a0p + 2560 + o);
    acc[0] = __builtin_amdgcn_mfma_f32_16x16x32_bf16(a0h, bh0, acc[0], 0,0,0);
    acc[1] = __builtin_amdgcn_mfma_f32_16x16x32_bf16(a0h, bh1, acc[1], 0,0,0);
    acc[0] = __builtin_amdgcn_mfma_f32_16x16x32_bf16(a0h, bl0, acc[0], 0,0,0);
    acc[1] = __builtin_amdgcn_mfma_f32_16x16x32_bf16(a0h, bl1, acc[1], 0,0,0);
    acc[0] = __builtin_amdgcn_mfma_f32_16x16x32_bf16(a0l, bh0, acc[0], 0,0,0);
    acc[1] = __builtin_amdgcn_mfma_f32_16x16x32_bf16(a0l, bh1, acc[1], 0,0,0);
  }

  #pragma unroll
  for (int g = 0; g < 2; g++)
    #pragma unroll
    for (int q = 0; q < 4; q++)
      red[w][kq*4 + q][16*g + ln] = acc[g][q];
  __syncthreads();
  #pragma unroll
  for (int j = 0; j < 2; j++){
    const int idx = tid + (j << 8);
    const int r = idx & 15, s = idx >> 4;
    float v = red[0][r][s] + red[1][r][s] + red[2][r][s] + red[3][r][s];
    Ap_part[((size_t)kh*NS + s)*NIDX + R0 + r] = v;
  }
}

// ---------------- fused CG update (pAp, alpha, a/r, reortho, beta, p, basis, ps2) ----------------
// 32 blocks x 512 thr (8 waves); thread owns idx = tid + 512c, c<5
__global__ __launch_bounds__(512) void k_cg(
    const float* __restrict__ Ap_part, float* __restrict__ rr_arr, int k, int last,
    float* __restrict__ pv, unsigned short* __restrict__ ps2,
    unsigned short* __restrict__ as2,
    float* __restrict__ av, float* __restrict__ rv, float* __restrict__ basis)
{
  __shared__ float wl[8];
  __shared__ float red[8][10];
  __shared__ float cbr[10];
  const int s = blockIdx.x, tid = threadIdx.x;
  const int w = tid >> 6;
  const size_t base = (size_t)s * NIDX;
  const float rr = rr_arr[s];

  float ap[5], pvv[5];
  #pragma unroll
  for (int c = 0; c < 5; c++){
    const int idx = tid + (c << 9);
    float apv = 0.f;
    #pragma unroll
    for (int kc = 0; kc < 4; kc++)
      apv += Ap_part[((size_t)kc*NS + s)*NIDX + idx];
    ap[c]  = apv;
    pvv[c] = pv[base + idx];
  }
  float v = 0.f;
  #pragma unroll
  for (int c = 0; c < 5; c++) v += pvv[c] * ap[c];
  v = wave_red(v);
  if ((tid & 63) == 0) wl[w] = v;
  __syncthreads();
  const float pAp = wl[0]+wl[1]+wl[2]+wl[3]+wl[4]+wl[5]+wl[6]+wl[7];
  const float alpha = rr / (pAp + CG_EPS);

  float rn[5];
  #pragma unroll
  for (int c = 0; c < 5; c++){
    const int idx = tid + (c << 9);
    const float an = av[base + idx] + alpha * pvv[c];
    av[base + idx] = an;
    rn[c] = rv[base + idx] - alpha * ap[c];
    if (last){
      unsigned short hh = f2bf(an);
      as2[(size_t)s*5120 + idx]        = hh;
      as2[(size_t)s*5120 + 2560 + idx] = f2bf(an - bf2f(hh));
    }
  }

  for (int j = 0; j <= k; j++){
    float cv = 0.f;
    const float* brow = basis + (size_t)j * (NS*NIDX) + base;
    #pragma unroll
    for (int c = 0; c < 5; c++) cv += brow[tid + (c << 9)] * rn[c];
    cv = wave_red(cv);
    if ((tid & 63) == 0) red[w][j] = cv;
  }
  __syncthreads();
  if (tid <= k){
    float cs = 0.f;
    #pragma unroll
    for (int ww = 0; ww < 8; ww++) cs += red[ww][tid];
    cbr[tid] = cs;
  }
  __syncthreads();

  for (int j = 0; j <= k; j++){
    const float cc = cbr[j];
    const float* brow = basis + (size_t)j * (NS*NIDX) + base;
    #pragma unroll
    for (int c = 0; c < 5; c++) rn[c] -= brow[tid + (c << 9)] * cc;
  }

  float rr2 = 0.f;
  #pragma unroll
  for (int c = 0; c < 5; c++) rr2 += rn[c]*rn[c];
  rr2 = wave_red(rr2);
  __syncthreads();
  if ((tid & 63) == 0) wl[w] = rr2;
  __syncthreads();
  const float rrn = wl[0]+wl[1]+wl[2]+wl[3]+wl[4]+wl[5]+wl[6]+wl[7];
  const float beta = rrn / (rr + CG_EPS);
  const float inv  = 1.0f / (sqrtf(rrn) + CG_EPS);

  float* bnew = basis + (size_t)(k+1) * (NS*NIDX) + base;
  #pragma unroll
  for (int c = 0; c < 5; c++){
    const int idx = tid + (c << 9);
    const float pnew = rn[c] + beta * pvv[c];
    rv[base + idx] = rn[c];
    pv[base + idx] = pnew;
    bnew[idx] = rn[c] * inv;
    unsigned short hh = f2bf(pnew);
    ps2[(size_t)s*5120 + idx]        = hh;
    ps2[(size_t)s*5120 + 2560 + idx] = f2bf(pnew - bf2f(hh));
  }
  if (tid == 0) rr_arr[s] = rrn;
}

// ---------------- final: preds = out0 + si*b + (sk-si)*(M a) ----------------
__global__ __launch_bounds__(256) void k_final(
    const float* __restrict__ out0, const float* __restrict__ bvec,
    const float* __restrict__ Ap_part, const float* __restrict__ lp,
    const float* __restrict__ lsi, float* __restrict__ out)
{
  int gid = blockIdx.x * 256 + threadIdx.x;
  int s = gid / NIDX, idx = gid - s * NIDX;
  float sk = expf(-0.5f * lp[0]);
  float si = expf(lsi[0]);
  float ma = 0.f;
  #pragma unroll
  for (int kc = 0; kc < 4; kc++) ma += Ap_part[(size_t)kc*NS*NIDX + gid];
  out[gid] = out0[idx] + si * bvec[gid] + (sk - si) * ma;
}

// ---------------- launch ----------------
extern "C" void kernel_launch(void* const* d_in, const int* in_sizes, int n_in,
                              void* d_out, int out_size, void* d_ws, size_t ws_size,
                              hipStream_t stream)
{
  const float* x   = (const float*)d_in[0];
  const float* W1  = (const float*)d_in[1];
  const float* b1  = (const float*)d_in[2];
  const float* W2  = (const float*)d_in[3];
  const float* b2  = (const float*)d_in[4];
  const float* eW1 = (const float*)d_in[5];
  const float* eb1 = (const float*)d_in[6];
  const float* eW2 = (const float*)d_in[7];
  const float* eb2 = (const float*)d_in[8];
  const float* lp  = (const float*)d_in[9];
  const float* lsi = (const float*)d_in[10];
  float* outp = (float*)d_out;

  float* ws = (float*)d_ws;
  float* h        = ws;                       // 131072
  float* G        = h        + 131072;        // 131072
  float* Kx       = G        + 131072;        // 65536
  float* Kh       = Kx       + 65536;         // 65536
  float* E2f      = Kh       + 65536;         // 1310720 (2560x1024 bf16 hi|lo)
  float* x2f      = E2f      + 1310720;       // 131072  (256x1024 bf16 hi|lo)
  float* M2f      = x2f      + 131072;        // 6553600 (2560x5120 bf16 hi|lo); T aliases
  float* out0     = M2f      + 6553600;       // 2560
  float* bvec     = out0     + 2560;          // 81920
  float* rv       = bvec     + 81920;         // 81920
  float* pv       = rv       + 81920;         // 81920
  float* av       = pv       + 81920;         // 81920
  float* basis    = av       + 81920;         // 901120 (11*81920)
  float* Ap_part  = basis    + 901120;        // 327680 (4*32*2560)
  float* ps2f     = Ap_part  + 327680;        // 81920 floats (32x5120 ushorts hi|lo)
  float* as2f     = ps2f     + 81920;         // 81920 floats
  float* rr0_part = as2f     + 81920;         // 320
  float* rr_arr   = rr0_part + 320;           // 32
  // total ~10.11M floats = ~40.4 MB

  unsigned short* E2  = (unsigned short*)E2f;
  unsigned short* x2  = (unsigned short*)x2f;
  unsigned short* M2  = (unsigned short*)M2f;
  unsigned short* ps2 = (unsigned short*)ps2f;
  unsigned short* as2 = (unsigned short*)as2f;
  float* T = M2f;   // alias: T (4,194,304 floats) dead before M2 is built

  k_gemm_z   <<<dim3(8,4),   256, 0, stream>>>(x, W1, b1, h, G);
  k_buildE   <<<1280,        256, 0, stream>>>(G, W2, E2);
  k_prepx    <<<128,         256, 0, stream>>>(x, x2);
  k_gemm_kxkh<<<dim3(4,4,2), 256, 0, stream>>>(x, h, Kx, Kh);
  k_gemm_T   <<<dim3(8,32),  512, 0, stream>>>(x2, eW1, eb1, G, T);
  k_bvec     <<<320,         256, 0, stream>>>(T, W2, h, eW2, eb2, b2, bvec, out0, rr0_part);
  k_gemm_M   <<<dim3(40,20), 128, 0, stream>>>(E2, Kx, Kh, M2);  // overwrites T (dead)
  k_init     <<<320,         256, 0, stream>>>(bvec, rr0_part, rv, pv, av, basis, rr_arr, ps2);

  for (int k = 0; k < MAXIT; k++){
    k_matvec<<<dim3(160,4), 256, 0, stream>>>(M2, ps2, Ap_part);
    k_cg    <<<NS,          512, 0, stream>>>(Ap_part, rr_arr, k, (k == MAXIT-1),
                                              pv, ps2, as2, av, rv, basis);
  }

  k_matvec<<<dim3(160,4), 256, 0, stream>>>(M2, as2, Ap_part);
  k_final <<<320,         256, 0, stream>>>(out0, bvec, Ap_part, lp, lsi, outp);
}

// Round 13
// 389.211 us; speedup vs baseline: 1.0631x; 1.0631x over previous
//
#include <hip/hip_runtime.h>
#include <math.h>

#define BB    256      // batch
#define DIN   512
#define HD    512
#define DOUT  10
#define NS    32       // samples
#define NIDX  2560     // BB*DOUT
#define MAXIT 10
#define CG_EPS 1e-12f

typedef __attribute__((ext_vector_type(8))) short s16x8;   // 8 bf16 (4 VGPRs)
typedef __attribute__((ext_vector_type(4))) float f32x4;   // 4 fp32 acc

// ---------------- helpers ----------------
__device__ __forceinline__ float wave_red(float v){
  #pragma unroll
  for (int off = 32; off > 0; off >>= 1) v += __shfl_down(v, off, 64);
  return v;  // lane 0 holds total
}
__device__ __forceinline__ unsigned short f2bf(float f){
  unsigned u = __float_as_uint(f);
  return (unsigned short)((u + 0x7FFFu + ((u >> 16) & 1u)) >> 16);
}
__device__ __forceinline__ float bf2f(unsigned short h){
  return __uint_as_float((unsigned)h << 16);
}

typedef const __attribute__((address_space(1))) unsigned short gus_t;
typedef __attribute__((address_space(3))) unsigned short lus_t;
__device__ __forceinline__ void gload16(const unsigned short* g, unsigned short* l){
  // async global->LDS, 16B/lane; LDS dest = wave-uniform base + lane*16
  __builtin_amdgcn_global_load_lds((gus_t*)g, (lus_t*)l, 16, 0, 0);
}

// ---------------- forward: h, G ----------------
__global__ __launch_bounds__(256) void k_gemm_z(
    const float* __restrict__ x, const float* __restrict__ W1,
    const float* __restrict__ b1, float* __restrict__ h, float* __restrict__ G)
{
  __shared__ __align__(16) float Al[16][68];
  __shared__ __align__(16) float Bl[16][64];
  const int tid = threadIdx.x;
  const int m0 = blockIdx.y * 64, n0 = blockIdx.x * 64;
  const int tx = tid & 15, ty = tid >> 4;
  float acc[4][4] = {};
  for (int k0 = 0; k0 < DIN; k0 += 16){
    {
      int m = tid >> 2, kk = (tid & 3) << 2;
      float4 a = *(const float4*)(x + (size_t)(m0+m)*DIN + k0 + kk);
      Al[kk+0][m]=a.x; Al[kk+1][m]=a.y; Al[kk+2][m]=a.z; Al[kk+3][m]=a.w;
    }
    {
      int kk = tid >> 4, n = (tid & 15) << 2;
      *(float4*)&Bl[kk][n] = *(const float4*)(W1 + (size_t)(k0+kk)*HD + n0 + n);
    }
    __syncthreads();
    #pragma unroll
    for (int kk = 0; kk < 16; kk++){
      float4 av = *(const float4*)&Al[kk][ty<<2];
      float4 bv = *(const float4*)&Bl[kk][tx<<2];
      float aa[4]={av.x,av.y,av.z,av.w}, bb[4]={bv.x,bv.y,bv.z,bv.w};
      #pragma unroll
      for (int i=0;i<4;i++)
        #pragma unroll
        for (int j=0;j<4;j++) acc[i][j] += aa[i]*bb[j];
    }
    __syncthreads();
  }
  float4 b4 = *(const float4*)&b1[n0 + (tx<<2)];
  float bbv[4] = {b4.x,b4.y,b4.z,b4.w};
  #pragma unroll
  for (int i=0;i<4;i++){
    int m = m0 + (ty<<2) + i;
    float hh[4], gg[4];
    #pragma unroll
    for (int j=0;j<4;j++){ float t = tanhf(acc[i][j] + bbv[j]); hh[j]=t; gg[j]=1.0f-t*t; }
    *(float4*)&h[(size_t)m*HD + n0 + (tx<<2)] = make_float4(hh[0],hh[1],hh[2],hh[3]);
    *(float4*)&G[(size_t)m*HD + n0 + (tx<<2)] = make_float4(gg[0],gg[1],gg[2],gg[3]);
  }
}

// ---------------- Kx = x x^T + 1 ; Kh = h h^T + 1 ----------------
__global__ __launch_bounds__(256) void k_gemm_kxkh(
    const float* __restrict__ x, const float* __restrict__ h,
    float* __restrict__ Kx, float* __restrict__ Kh)
{
  __shared__ __align__(16) float Al[16][68];
  __shared__ __align__(16) float Bl[16][68];
  const int tid = threadIdx.x;
  const float* A = blockIdx.z ? h : x;
  float* C = blockIdx.z ? Kh : Kx;
  const int m0 = blockIdx.y * 64, n0 = blockIdx.x * 64;
  const int tx = tid & 15, ty = tid >> 4;
  float acc[4][4] = {};
  for (int k0 = 0; k0 < DIN; k0 += 16){
    {
      int m = tid >> 2, kk = (tid & 3) << 2;
      float4 a = *(const float4*)(A + (size_t)(m0+m)*DIN + k0 + kk);
      Al[kk+0][m]=a.x; Al[kk+1][m]=a.y; Al[kk+2][m]=a.z; Al[kk+3][m]=a.w;
      float4 b = *(const float4*)(A + (size_t)(n0+m)*DIN + k0 + kk);
      Bl[kk+0][m]=b.x; Bl[kk+1][m]=b.y; Bl[kk+2][m]=b.z; Bl[kk+3][m]=b.w;
    }
    __syncthreads();
    #pragma unroll
    for (int kk = 0; kk < 16; kk++){
      float4 av = *(const float4*)&Al[kk][ty<<2];
      float4 bv = *(const float4*)&Bl[kk][tx<<2];
      float aa[4]={av.x,av.y,av.z,av.w}, bb[4]={bv.x,bv.y,bv.z,bv.w};
      #pragma unroll
      for (int i=0;i<4;i++)
        #pragma unroll
        for (int j=0;j<4;j++) acc[i][j] += aa[i]*bb[j];
    }
    __syncthreads();
  }
  #pragma unroll
  for (int i=0;i<4;i++){
    int m = m0 + (ty<<2) + i;
    *(float4*)&C[(size_t)m*BB + n0 + (tx<<2)] =
        make_float4(acc[i][0]+1.0f, acc[i][1]+1.0f, acc[i][2]+1.0f, acc[i][3]+1.0f);
  }
}

// ---------------- E2 = [Ehi | Elo] bf16, E[(b,o)][j] = G[b][j]*W2[j][o] ----------------
__global__ __launch_bounds__(256) void k_buildE(
    const float* __restrict__ G, const float* __restrict__ W2,
    unsigned short* __restrict__ E2)
{
  int gid = blockIdx.x * 256 + threadIdx.x;   // 2560 rows * 128 j4-chunks
  int row = gid >> 7, j4 = (gid & 127) << 2;
  int b = row / 10, o = row - b * 10;
  float4 g = *(const float4*)&G[(size_t)b*HD + j4];
  float e[4] = { g.x * W2[(j4+0)*DOUT + o], g.y * W2[(j4+1)*DOUT + o],
                 g.z * W2[(j4+2)*DOUT + o], g.w * W2[(j4+3)*DOUT + o] };
  unsigned short hi[4], lo[4];
  #pragma unroll
  for (int r = 0; r < 4; r++){
    hi[r] = f2bf(e[r]);
    lo[r] = f2bf(e[r] - bf2f(hi[r]));
  }
  *(ushort4*)&E2[(size_t)row*1024 + j4]       = make_ushort4(hi[0],hi[1],hi[2],hi[3]);
  *(ushort4*)&E2[(size_t)row*1024 + 512 + j4] = make_ushort4(lo[0],lo[1],lo[2],lo[3]);
}

// ---------------- x2 = [xhi | xlo] bf16 ----------------
__global__ __launch_bounds__(256) void k_prepx(
    const float* __restrict__ x, unsigned short* __restrict__ x2)
{
  int gid = blockIdx.x * 256 + threadIdx.x;   // 256 rows * 128 j4-chunks
  int row = gid >> 7, j4 = (gid & 127) << 2;
  float4 v = *(const float4*)&x[(size_t)row*DIN + j4];
  float e[4] = {v.x, v.y, v.z, v.w};
  unsigned short hi[4], lo[4];
  #pragma unroll
  for (int r = 0; r < 4; r++){
    hi[r] = f2bf(e[r]);
    lo[r] = f2bf(e[r] - bf2f(hi[r]));
  }
  *(ushort4*)&x2[(size_t)row*1024 + j4]       = make_ushort4(hi[0],hi[1],hi[2],hi[3]);
  *(ushort4*)&x2[(size_t)row*1024 + 512 + j4] = make_ushort4(lo[0],lo[1],lo[2],lo[3]);
}

// ---------------- M2 = split-bf16 of (Kx .* (E E^T) + delta_{oo'} Kh) ----------------
// R11-proven LDS-staged MFMA GEMM, BK=64. Tile 128m x 64n, 800 blocks (XCD-swizzled
// 1D grid), 128 thr (2 waves). 24 K-steps over 3 phases (hi*hi, hi*lo, lo*hi).
// Staging via global_load_lds w=16 with XOR-swizzled source chunks (T2; rule #21).
__global__ __launch_bounds__(128) void k_gemm_M(
    const unsigned short* __restrict__ E2, const float* __restrict__ Kx,
    const float* __restrict__ Kh, unsigned short* __restrict__ M2)
{
  __shared__ __align__(16) unsigned short As[128*64];   // 16 KB, row stride 64 elems
  __shared__ __align__(16) unsigned short Bs[64*64];    // 8 KB
  const int tid = threadIdx.x;
  const int w = tid >> 6, l = tid & 63;
  const int ln = l & 15, kq = l >> 4;
  // T1 bijective XCD swizzle: 800 = 8 XCDs x 100 contiguous tiles
  const int orig = blockIdx.x;
  const int wg = (orig & 7) * 100 + (orig >> 3);
  const int m0 = (wg / 40) << 7, n0 = (wg % 40) << 6;

  // staging: chunk idx = c*128 + tid -> row = c*16 + (tid>>3), colchunk = tid&7,
  // source colchunk = (tid&7) ^ (row&7)   [swizzle involution]
  const int srow = tid >> 3;
  const int scc  = (tid & 7) ^ (srow & 7);
  const unsigned short* gA = E2 + (size_t)(m0 + srow)*1024 + scc*8;
  const unsigned short* gB = E2 + (size_t)(n0 + srow)*1024 + scc*8;
  unsigned short* lA = As + ((tid & 64) << 3);   // wave-uniform base (+1024/call)
  unsigned short* lB = Bs + ((tid & 64) << 3);

  f32x4 acc[4][4];
  #pragma unroll
  for (int i = 0; i < 4; i++)
    #pragma unroll
    for (int j = 0; j < 4; j++)
      acc[i][j] = (f32x4){0.f, 0.f, 0.f, 0.f};

  const int xs = ln & 7;   // read-side swizzle key (row&7 == ln&7 for 16-aligned frag rows)

  for (int t = 0; t < 24; ++t){
    const int p = t >> 3, k8 = t & 7;
    const int oa = ((p == 2) ? 512 : 0) + (k8 << 6);
    const int ob = ((p == 1) ? 512 : 0) + (k8 << 6);
    #pragma unroll
    for (int c = 0; c < 8; c++)
      gload16(gA + (size_t)c*16*1024 + oa, lA + c*1024);
    #pragma unroll
    for (int c = 0; c < 4; c++)
      gload16(gB + (size_t)c*16*1024 + ob, lB + c*1024);
    __syncthreads();   // drains vmcnt (gload_lds) before LDS reads

    #pragma unroll
    for (int kk = 0; kk < 2; kk++){
      const int kc = kq + (kk << 2);          // 8-elem chunk index 0..7
      const int co = (kc ^ xs) << 3;          // swizzled elem offset within row
      s16x8 af[4], bf[4];
      #pragma unroll
      for (int f = 0; f < 4; f++){
        af[f] = *(const s16x8*)(As + ((w<<6) + (f<<4) + ln)*64 + co);
        bf[f] = *(const s16x8*)(Bs + ((f<<4) + ln)*64 + co);
      }
      #pragma unroll
      for (int fi = 0; fi < 4; fi++)
        #pragma unroll
        for (int fj = 0; fj < 4; fj++)
          acc[fi][fj] = __builtin_amdgcn_mfma_f32_16x16x32_bf16(
              af[fi], bf[fj], acc[fi][fj], 0, 0, 0);
    }
    __syncthreads();   // LDS reuse next step
  }

  // epilogue: v = Kx*acc (+ Kh on o-diagonal); split-bf16 write, coalesced rows
  const int mb = m0 + (w << 6);
  int bmv[4][4], omv[4][4], bnv[4], onv[4];
  #pragma unroll
  for (int f = 0; f < 4; f++){
    int n = n0 + f*16 + ln; bnv[f] = n / 10; onv[f] = n - bnv[f]*10;
    #pragma unroll
    for (int r = 0; r < 4; r++){
      int m = mb + f*16 + kq*4 + r;
      bmv[f][r] = m / 10; omv[f][r] = m - bmv[f][r]*10;
    }
  }
  #pragma unroll
  for (int fi = 0; fi < 4; fi++)
    #pragma unroll
    for (int r = 0; r < 4; r++){
      const int m = mb + fi*16 + kq*4 + r;
      #pragma unroll
      for (int fj = 0; fj < 4; fj++){
        const int n = n0 + fj*16 + ln;
        float v = Kx[(size_t)bmv[fi][r]*BB + bnv[fj]] * acc[fi][fj][r];
        if (omv[fi][r] == onv[fj]) v += Kh[(size_t)bmv[fi][r]*BB + bnv[fj]];
        unsigned short hv = f2bf(v);
        M2[(size_t)m*5120 + n]        = hv;
        M2[(size_t)m*5120 + 2560 + n] = f2bf(v - bf2f(hv));
      }
    }
}

// ---------------- T[s] = (x @ eps_W1[s] + eps_b1[s]) * G  via split-bf16 MFMA ----------------
// grid (8 n-tiles, 32 samples) x 512 thr (8 waves). Wave w owns m-frags {2w, 2w+1}.
__global__ __launch_bounds__(512) void k_gemm_T(
    const unsigned short* __restrict__ x2, const float* __restrict__ eW1,
    const float* __restrict__ eb1, const float* __restrict__ G,
    float* __restrict__ T)
{
  const int tid = threadIdx.x;
  const int w = tid >> 6, l = tid & 63;
  const int ln = l & 15, kq = l >> 4;
  const int n0 = blockIdx.x << 6;
  const int s  = blockIdx.y;
  const float* Wb = eW1 + (size_t)s * DIN * HD;

  const unsigned short* pa[2];
  #pragma unroll
  for (int f = 0; f < 2; f++)
    pa[f] = x2 + (size_t)(16*(2*w + f) + ln) * 1024 + kq * 8;

  f32x4 acc[2][4];
  #pragma unroll
  for (int i = 0; i < 2; i++)
    #pragma unroll
    for (int j = 0; j < 4; j++)
      acc[i][j] = (f32x4){0.f, 0.f, 0.f, 0.f};

  #pragma unroll 2
  for (int k0 = 0; k0 < DIN; k0 += 32){
    float wv[4][8];
    const float* wp = Wb + (size_t)(k0 + kq*8)*HD + n0 + ln;
    #pragma unroll
    for (int i = 0; i < 8; i++)
      #pragma unroll
      for (int f = 0; f < 4; f++)
        wv[f][i] = wp[(size_t)i*HD + 16*f];

    s16x8 ahi[2], alo[2], bhi[4], blo[4];
    #pragma unroll
    for (int f = 0; f < 2; f++){
      ahi[f] = *(const s16x8*)(pa[f] + k0);
      alo[f] = *(const s16x8*)(pa[f] + 512 + k0);
    }
    #pragma unroll
    for (int f = 0; f < 4; f++)
      #pragma unroll
      for (int i = 0; i < 8; i++){
        unsigned short hh = f2bf(wv[f][i]);
        bhi[f][i] = (short)hh;
        blo[f][i] = (short)f2bf(wv[f][i] - bf2f(hh));
      }
    #pragma unroll
    for (int fi = 0; fi < 2; fi++)
      #pragma unroll
      for (int fj = 0; fj < 4; fj++){
        acc[fi][fj] = __builtin_amdgcn_mfma_f32_16x16x32_bf16(ahi[fi], bhi[fj], acc[fi][fj], 0,0,0);
        acc[fi][fj] = __builtin_amdgcn_mfma_f32_16x16x32_bf16(ahi[fi], blo[fj], acc[fi][fj], 0,0,0);
        acc[fi][fj] = __builtin_amdgcn_mfma_f32_16x16x32_bf16(alo[fi], bhi[fj], acc[fi][fj], 0,0,0);
      }
  }

  #pragma unroll
  for (int fj = 0; fj < 4; fj++){
    const int n = n0 + 16*fj + ln;
    const float eb = eb1[(size_t)s*HD + n];
    #pragma unroll
    for (int fi = 0; fi < 2; fi++)
      #pragma unroll
      for (int q = 0; q < 4; q++){
        const int m = 16*(2*w + fi) + kq*4 + q;
        T[((size_t)s*BB + m)*HD + n] = (acc[fi][fj][q] + eb) * G[(size_t)m*HD + n];
      }
  }
}

// ---------------- bvec (+ out0 for s==0 blocks) ----------------
__global__ __launch_bounds__(256) void k_bvec(
    const float* __restrict__ T, const float* __restrict__ W2,
    const float* __restrict__ h, const float* __restrict__ eW2,
    const float* __restrict__ eb2, const float* __restrict__ b2,
    float* __restrict__ bvec, float* __restrict__ out0, float* __restrict__ rr0_part)
{
  __shared__ __align__(16) float W2t[10][516];
  __shared__ __align__(16) float E2t[10][516];
  __shared__ float wl[4];
  const int tid = threadIdx.x, bid = blockIdx.x;
  const int s = bid / 10;
  const int idx = (bid % 10) * 256 + tid;
  const int b = idx / 10, o = idx - b*10;
  const float* e2 = eW2 + (size_t)s * HD * DOUT;
  for (int i = tid; i < HD*DOUT; i += 256){
    int k = i / 10, oo = i - k*10;
    W2t[oo][k] = W2[i];
    E2t[oo][k] = e2[i];
  }
  __syncthreads();
  const float* Tr = T + ((size_t)s*BB + b) * HD;
  const float* hr = h + (size_t)b * HD;
  const bool do0 = (bid < 10);
  float acc = eb2[s*DOUT + o];
  float a0 = 0.f;
  #pragma unroll 4
  for (int k4 = 0; k4 < HD/4; k4++){
    float4 t4 = *(const float4*)(Tr + (k4<<2));
    float4 h4 = *(const float4*)(hr + (k4<<2));
    float4 w4 = *(const float4*)&W2t[o][k4<<2];
    float4 q4 = *(const float4*)&E2t[o][k4<<2];
    acc += t4.x*w4.x + t4.y*w4.y + t4.z*w4.z + t4.w*w4.w
         + h4.x*q4.x + h4.y*q4.y + h4.z*q4.z + h4.w*q4.w;
    if (do0) a0 += h4.x*w4.x + h4.y*w4.y + h4.z*w4.z + h4.w*w4.w;
  }
  bvec[(size_t)s*NIDX + idx] = acc;
  if (do0) out0[idx] = a0 + b2[o];
  float v = wave_red(acc * acc);
  if ((tid & 63) == 0) wl[tid >> 6] = v;
  __syncthreads();
  if (tid == 0) rr0_part[bid] = wl[0]+wl[1]+wl[2]+wl[3];
}

// ---------------- CG init ----------------
__global__ __launch_bounds__(256) void k_init(
    const float* __restrict__ bvec, const float* __restrict__ rr0_part,
    float* __restrict__ r, float* __restrict__ p, float* __restrict__ a,
    float* __restrict__ basis, float* __restrict__ rr_arr,
    unsigned short* __restrict__ ps2)
{
  int gid = blockIdx.x * 256 + threadIdx.x;
  int s = gid / NIDX, idx = gid - s * NIDX;
  float rr0 = 0.f;
  #pragma unroll
  for (int i = 0; i < 10; i++) rr0 += rr0_part[s*10 + i];
  float bv = bvec[gid];
  r[gid] = bv; p[gid] = bv; a[gid] = 0.f;
  basis[gid] = bv / (sqrtf(rr0) + CG_EPS);
  unsigned short hh = f2bf(bv);
  ps2[(size_t)s*5120 + idx]        = hh;
  ps2[(size_t)s*5120 + 2560 + idx] = f2bf(bv - bf2f(hh));
  if (threadIdx.x == 0) rr_arr[s] = rr0;
}

// ---------------- matvec: Ap_part[kh][s][r] via split-bf16 MFMA ----------------
// grid (160 row-blocks of 16, 4 K-quarters), 256 thr (4 waves, wave = 160-col slice).
__global__ __launch_bounds__(256) void k_matvec(
    const unsigned short* __restrict__ M2, const unsigned short* __restrict__ p2,
    float* __restrict__ Ap_part)
{
  __shared__ float red[4][16][33];
  const int tid = threadIdx.x;
  const int w = tid >> 6, l = tid & 63;
  const int ln = l & 15, kq = l >> 4;
  const int R0 = blockIdx.x << 4;
  const int kh = blockIdx.y;                 // 0..3
  const int c0 = kh*640 + w*160;

  const unsigned short* a0p = M2 + (size_t)(R0 + ln)*5120 + c0 + kq*8;
  const unsigned short* q0  = p2 + (size_t)ln*5120        + c0 + kq*8;
  const unsigned short* q1  = p2 + (size_t)(16 + ln)*5120 + c0 + kq*8;

  f32x4 acc[2];
  acc[0] = (f32x4){0.f,0.f,0.f,0.f};
  acc[1] = (f32x4){0.f,0.f,0.f,0.f};

  #pragma unroll
  for (int ch = 0; ch < 5; ch++){
    const int o = ch * 32;
    s16x8 bh0 = *(const s16x8*)(q0 + o);
    s16x8 bl0 = *(const s16x8*)(q0 + 2560 + o);
    s16x8 bh1 = *(const s16x8*)(q1 + o);
    s16x8 bl1 = *(const s16x8*)(q1 + 2560 + o);
    s16x8 a0h = *(const s16x8*)(a0p + o);
    s16x8 a0l = *(const s16x8*)(a0p + 2560 + o);
    acc[0] = __builtin_amdgcn_mfma_f32_16x16x32_bf16(a0h, bh0, acc[0], 0,0,0);
    acc[1] = __builtin_amdgcn_mfma_f32_16x16x32_bf16(a0h, bh1, acc[1], 0,0,0);
    acc[0] = __builtin_amdgcn_mfma_f32_16x16x32_bf16(a0h, bl0, acc[0], 0,0,0);
    acc[1] = __builtin_amdgcn_mfma_f32_16x16x32_bf16(a0h, bl1, acc[1], 0,0,0);
    acc[0] = __builtin_amdgcn_mfma_f32_16x16x32_bf16(a0l, bh0, acc[0], 0,0,0);
    acc[1] = __builtin_amdgcn_mfma_f32_16x16x32_bf16(a0l, bh1, acc[1], 0,0,0);
  }

  #pragma unroll
  for (int g = 0; g < 2; g++)
    #pragma unroll
    for (int q = 0; q < 4; q++)
      red[w][kq*4 + q][16*g + ln] = acc[g][q];
  __syncthreads();
  #pragma unroll
  for (int j = 0; j < 2; j++){
    const int idx = tid + (j << 8);
    const int r = idx & 15, s = idx >> 4;
    float v = red[0][r][s] + red[1][r][s] + red[2][r][s] + red[3][r][s];
    Ap_part[((size_t)kh*NS + s)*NIDX + R0 + r] = v;
  }
}

// ---------------- fused CG update (pAp, alpha, a/r, reortho, beta, p, basis, ps2) ----------------
// 32 blocks x 512 thr (8 waves); thread owns idx = tid + 512c, c<5
__global__ __launch_bounds__(512) void k_cg(
    const float* __restrict__ Ap_part, float* __restrict__ rr_arr, int k, int last,
    float* __restrict__ pv, unsigned short* __restrict__ ps2,
    unsigned short* __restrict__ as2,
    float* __restrict__ av, float* __restrict__ rv, float* __restrict__ basis)
{
  __shared__ float wl[8];
  __shared__ float red[8][10];
  __shared__ float cbr[10];
  const int s = blockIdx.x, tid = threadIdx.x;
  const int w = tid >> 6;
  const size_t base = (size_t)s * NIDX;
  const float rr = rr_arr[s];

  float ap[5], pvv[5];
  #pragma unroll
  for (int c = 0; c < 5; c++){
    const int idx = tid + (c << 9);
    float apv = 0.f;
    #pragma unroll
    for (int kc = 0; kc < 4; kc++)
      apv += Ap_part[((size_t)kc*NS + s)*NIDX + idx];
    ap[c]  = apv;
    pvv[c] = pv[base + idx];
  }
  float v = 0.f;
  #pragma unroll
  for (int c = 0; c < 5; c++) v += pvv[c] * ap[c];
  v = wave_red(v);
  if ((tid & 63) == 0) wl[w] = v;
  __syncthreads();
  const float pAp = wl[0]+wl[1]+wl[2]+wl[3]+wl[4]+wl[5]+wl[6]+wl[7];
  const float alpha = rr / (pAp + CG_EPS);

  float rn[5];
  #pragma unroll
  for (int c = 0; c < 5; c++){
    const int idx = tid + (c << 9);
    const float an = av[base + idx] + alpha * pvv[c];
    av[base + idx] = an;
    rn[c] = rv[base + idx] - alpha * ap[c];
    if (last){
      unsigned short hh = f2bf(an);
      as2[(size_t)s*5120 + idx]        = hh;
      as2[(size_t)s*5120 + 2560 + idx] = f2bf(an - bf2f(hh));
    }
  }

  for (int j = 0; j <= k; j++){
    float cv = 0.f;
    const float* brow = basis + (size_t)j * (NS*NIDX) + base;
    #pragma unroll
    for (int c = 0; c < 5; c++) cv += brow[tid + (c << 9)] * rn[c];
    cv = wave_red(cv);
    if ((tid & 63) == 0) red[w][j] = cv;
  }
  __syncthreads();
  if (tid <= k){
    float cs = 0.f;
    #pragma unroll
    for (int ww = 0; ww < 8; ww++) cs += red[ww][tid];
    cbr[tid] = cs;
  }
  __syncthreads();

  for (int j = 0; j <= k; j++){
    const float cc = cbr[j];
    const float* brow = basis + (size_t)j * (NS*NIDX) + base;
    #pragma unroll
    for (int c = 0; c < 5; c++) rn[c] -= brow[tid + (c << 9)] * cc;
  }

  float rr2 = 0.f;
  #pragma unroll
  for (int c = 0; c < 5; c++) rr2 += rn[c]*rn[c];
  rr2 = wave_red(rr2);
  __syncthreads();
  if ((tid & 63) == 0) wl[w] = rr2;
  __syncthreads();
  const float rrn = wl[0]+wl[1]+wl[2]+wl[3]+wl[4]+wl[5]+wl[6]+wl[7];
  const float beta = rrn / (rr + CG_EPS);
  const float inv  = 1.0f / (sqrtf(rrn) + CG_EPS);

  float* bnew = basis + (size_t)(k+1) * (NS*NIDX) + base;
  #pragma unroll
  for (int c = 0; c < 5; c++){
    const int idx = tid + (c << 9);
    const float pnew = rn[c] + beta * pvv[c];
    rv[base + idx] = rn[c];
    pv[base + idx] = pnew;
    bnew[idx] = rn[c] * inv;
    unsigned short hh = f2bf(pnew);
    ps2[(size_t)s*5120 + idx]        = hh;
    ps2[(size_t)s*5120 + 2560 + idx] = f2bf(pnew - bf2f(hh));
  }
  if (tid == 0) rr_arr[s] = rrn;
}

// ---------------- final: preds = out0 + si*b + (sk-si)*(M a) ----------------
__global__ __launch_bounds__(256) void k_final(
    const float* __restrict__ out0, const float* __restrict__ bvec,
    const float* __restrict__ Ap_part, const float* __restrict__ lp,
    const float* __restrict__ lsi, float* __restrict__ out)
{
  int gid = blockIdx.x * 256 + threadIdx.x;
  int s = gid / NIDX, idx = gid - s * NIDX;
  float sk = expf(-0.5f * lp[0]);
  float si = expf(lsi[0]);
  float ma = 0.f;
  #pragma unroll
  for (int kc = 0; kc < 4; kc++) ma += Ap_part[(size_t)kc*NS*NIDX + gid];
  out[gid] = out0[idx] + si * bvec[gid] + (sk - si) * ma;
}

// ---------------- launch ----------------
extern "C" void kernel_launch(void* const* d_in, const int* in_sizes, int n_in,
                              void* d_out, int out_size, void* d_ws, size_t ws_size,
                              hipStream_t stream)
{
  const float* x   = (const float*)d_in[0];
  const float* W1  = (const float*)d_in[1];
  const float* b1  = (const float*)d_in[2];
  const float* W2  = (const float*)d_in[3];
  const float* b2  = (const float*)d_in[4];
  const float* eW1 = (const float*)d_in[5];
  const float* eb1 = (const float*)d_in[6];
  const float* eW2 = (const float*)d_in[7];
  const float* eb2 = (const float*)d_in[8];
  const float* lp  = (const float*)d_in[9];
  const float* lsi = (const float*)d_in[10];
  float* outp = (float*)d_out;

  float* ws = (float*)d_ws;
  float* h        = ws;                       // 131072
  float* G        = h        + 131072;        // 131072
  float* Kx       = G        + 131072;        // 65536
  float* Kh       = Kx       + 65536;         // 65536
  float* E2f      = Kh       + 65536;         // 1310720 (2560x1024 bf16 hi|lo)
  float* x2f      = E2f      + 1310720;       // 131072  (256x1024 bf16 hi|lo)
  float* M2f      = x2f      + 131072;        // 6553600 (2560x5120 bf16 hi|lo); T aliases
  float* out0     = M2f      + 6553600;       // 2560
  float* bvec     = out0     + 2560;          // 81920
  float* rv       = bvec     + 81920;         // 81920
  float* pv       = rv       + 81920;         // 81920
  float* av       = pv       + 81920;         // 81920
  float* basis    = av       + 81920;         // 901120 (11*81920)
  float* Ap_part  = basis    + 901120;        // 327680 (4*32*2560)
  float* ps2f     = Ap_part  + 327680;        // 81920 floats (32x5120 ushorts hi|lo)
  float* as2f     = ps2f     + 81920;         // 81920 floats
  float* rr0_part = as2f     + 81920;         // 320
  float* rr_arr   = rr0_part + 320;           // 32
  // total ~10.11M floats = ~40.4 MB

  unsigned short* E2  = (unsigned short*)E2f;
  unsigned short* x2  = (unsigned short*)x2f;
  unsigned short* M2  = (unsigned short*)M2f;
  unsigned short* ps2 = (unsigned short*)ps2f;
  unsigned short* as2 = (unsigned short*)as2f;
  float* T = M2f;   // alias: T (4,194,304 floats) dead before M2 is built

  k_gemm_z   <<<dim3(8,4),   256, 0, stream>>>(x, W1, b1, h, G);
  k_buildE   <<<1280,        256, 0, stream>>>(G, W2, E2);
  k_prepx    <<<128,         256, 0, stream>>>(x, x2);
  k_gemm_kxkh<<<dim3(4,4,2), 256, 0, stream>>>(x, h, Kx, Kh);
  k_gemm_T   <<<dim3(8,32),  512, 0, stream>>>(x2, eW1, eb1, G, T);
  k_bvec     <<<320,         256, 0, stream>>>(T, W2, h, eW2, eb2, b2, bvec, out0, rr0_part);
  k_gemm_M   <<<800,         128, 0, stream>>>(E2, Kx, Kh, M2);  // overwrites T (dead)
  k_init     <<<320,         256, 0, stream>>>(bvec, rr0_part, rv, pv, av, basis, rr_arr, ps2);

  for (int k = 0; k < MAXIT; k++){
    k_matvec<<<dim3(160,4), 256, 0, stream>>>(M2, ps2, Ap_part);
    k_cg    <<<NS,          512, 0, stream>>>(Ap_part, rr_arr, k, (k == MAXIT-1),
                                              pv, ps2, as2, av, rv, basis);
  }

  k_matvec<<<dim3(160,4), 256, 0, stream>>>(M2, as2, Ap_part);
  k_final <<<320,         256, 0, stream>>>(out0, bvec, Ap_part, lp, lsi, outp);
}

// Round 14
// 374.363 us; speedup vs baseline: 1.1053x; 1.0397x over previous
//
#include <hip/hip_runtime.h>
#include <math.h>

#define BB    256      // batch
#define DIN   512
#define HD    512
#define DOUT  10
#define NS    32       // samples
#define NIDX  2560     // BB*DOUT
#define MAXIT 10
#define CG_EPS 1e-12f

typedef __attribute__((ext_vector_type(8))) short s16x8;     // 8 bf16 (4 VGPRs)
typedef __attribute__((ext_vector_type(4))) float f32x4;     // 4 fp32 acc
typedef __attribute__((ext_vector_type(4))) unsigned u32x4;  // 4 dwords

// ---------------- helpers ----------------
__device__ __forceinline__ float wave_red(float v){
  #pragma unroll
  for (int off = 32; off > 0; off >>= 1) v += __shfl_down(v, off, 64);
  return v;  // lane 0 holds total
}
__device__ __forceinline__ unsigned short f2bf(float f){
  unsigned u = __float_as_uint(f);
  return (unsigned short)((u + 0x7FFFu + ((u >> 16) & 1u)) >> 16);
}
__device__ __forceinline__ float bf2f(unsigned short h){
  return __uint_as_float((unsigned)h << 16);
}
// HW packed cvt (RNE, same bits as f2bf): dst.lo = bf16(a), dst.hi = bf16(b)
__device__ __forceinline__ unsigned cvt_pk_bf16(float a, float b){
  unsigned r;
  asm("v_cvt_pk_bf16_f32 %0, %1, %2" : "=v"(r) : "v"(a), "v"(b));
  return r;
}

typedef const __attribute__((address_space(1))) unsigned short gus_t;
typedef __attribute__((address_space(3))) unsigned short lus_t;
__device__ __forceinline__ void gload16(const unsigned short* g, unsigned short* l){
  // async global->LDS, 16B/lane; LDS dest = wave-uniform base + lane*16
  __builtin_amdgcn_global_load_lds((gus_t*)g, (lus_t*)l, 16, 0, 0);
}

// ---------------- forward: h, G ----------------
__global__ __launch_bounds__(256) void k_gemm_z(
    const float* __restrict__ x, const float* __restrict__ W1,
    const float* __restrict__ b1, float* __restrict__ h, float* __restrict__ G)
{
  __shared__ __align__(16) float Al[16][68];
  __shared__ __align__(16) float Bl[16][64];
  const int tid = threadIdx.x;
  const int m0 = blockIdx.y * 64, n0 = blockIdx.x * 64;
  const int tx = tid & 15, ty = tid >> 4;
  float acc[4][4] = {};
  for (int k0 = 0; k0 < DIN; k0 += 16){
    {
      int m = tid >> 2, kk = (tid & 3) << 2;
      float4 a = *(const float4*)(x + (size_t)(m0+m)*DIN + k0 + kk);
      Al[kk+0][m]=a.x; Al[kk+1][m]=a.y; Al[kk+2][m]=a.z; Al[kk+3][m]=a.w;
    }
    {
      int kk = tid >> 4, n = (tid & 15) << 2;
      *(float4*)&Bl[kk][n] = *(const float4*)(W1 + (size_t)(k0+kk)*HD + n0 + n);
    }
    __syncthreads();
    #pragma unroll
    for (int kk = 0; kk < 16; kk++){
      float4 av = *(const float4*)&Al[kk][ty<<2];
      float4 bv = *(const float4*)&Bl[kk][tx<<2];
      float aa[4]={av.x,av.y,av.z,av.w}, bb[4]={bv.x,bv.y,bv.z,bv.w};
      #pragma unroll
      for (int i=0;i<4;i++)
        #pragma unroll
        for (int j=0;j<4;j++) acc[i][j] += aa[i]*bb[j];
    }
    __syncthreads();
  }
  float4 b4 = *(const float4*)&b1[n0 + (tx<<2)];
  float bbv[4] = {b4.x,b4.y,b4.z,b4.w};
  #pragma unroll
  for (int i=0;i<4;i++){
    int m = m0 + (ty<<2) + i;
    float hh[4], gg[4];
    #pragma unroll
    for (int j=0;j<4;j++){ float t = tanhf(acc[i][j] + bbv[j]); hh[j]=t; gg[j]=1.0f-t*t; }
    *(float4*)&h[(size_t)m*HD + n0 + (tx<<2)] = make_float4(hh[0],hh[1],hh[2],hh[3]);
    *(float4*)&G[(size_t)m*HD + n0 + (tx<<2)] = make_float4(gg[0],gg[1],gg[2],gg[3]);
  }
}

// ---------------- Kx = x x^T + 1 ; Kh = h h^T + 1 ----------------
__global__ __launch_bounds__(256) void k_gemm_kxkh(
    const float* __restrict__ x, const float* __restrict__ h,
    float* __restrict__ Kx, float* __restrict__ Kh)
{
  __shared__ __align__(16) float Al[16][68];
  __shared__ __align__(16) float Bl[16][68];
  const int tid = threadIdx.x;
  const float* A = blockIdx.z ? h : x;
  float* C = blockIdx.z ? Kh : Kx;
  const int m0 = blockIdx.y * 64, n0 = blockIdx.x * 64;
  const int tx = tid & 15, ty = tid >> 4;
  float acc[4][4] = {};
  for (int k0 = 0; k0 < DIN; k0 += 16){
    {
      int m = tid >> 2, kk = (tid & 3) << 2;
      float4 a = *(const float4*)(A + (size_t)(m0+m)*DIN + k0 + kk);
      Al[kk+0][m]=a.x; Al[kk+1][m]=a.y; Al[kk+2][m]=a.z; Al[kk+3][m]=a.w;
      float4 b = *(const float4*)(A + (size_t)(n0+m)*DIN + k0 + kk);
      Bl[kk+0][m]=b.x; Bl[kk+1][m]=b.y; Bl[kk+2][m]=b.z; Bl[kk+3][m]=b.w;
    }
    __syncthreads();
    #pragma unroll
    for (int kk = 0; kk < 16; kk++){
      float4 av = *(const float4*)&Al[kk][ty<<2];
      float4 bv = *(const float4*)&Bl[kk][tx<<2];
      float aa[4]={av.x,av.y,av.z,av.w}, bb[4]={bv.x,bv.y,bv.z,bv.w};
      #pragma unroll
      for (int i=0;i<4;i++)
        #pragma unroll
        for (int j=0;j<4;j++) acc[i][j] += aa[i]*bb[j];
    }
    __syncthreads();
  }
  #pragma unroll
  for (int i=0;i<4;i++){
    int m = m0 + (ty<<2) + i;
    *(float4*)&C[(size_t)m*BB + n0 + (tx<<2)] =
        make_float4(acc[i][0]+1.0f, acc[i][1]+1.0f, acc[i][2]+1.0f, acc[i][3]+1.0f);
  }
}

// ---------------- fused: E2 = split(G*W2col) rows 0..1279; x2 = split(x) rest --------
__global__ __launch_bounds__(256) void k_buildEx(
    const float* __restrict__ G, const float* __restrict__ W2,
    const float* __restrict__ x,
    unsigned short* __restrict__ E2, unsigned short* __restrict__ x2)
{
  const int tid = threadIdx.x, bid = blockIdx.x;
  if (bid < 1280){
    int gid = bid * 256 + tid;                // 2560 rows * 128 j4-chunks
    int row = gid >> 7, j4 = (gid & 127) << 2;
    int b = row / 10, o = row - b * 10;
    float4 g = *(const float4*)&G[(size_t)b*HD + j4];
    float e[4] = { g.x * W2[(j4+0)*DOUT + o], g.y * W2[(j4+1)*DOUT + o],
                   g.z * W2[(j4+2)*DOUT + o], g.w * W2[(j4+3)*DOUT + o] };
    unsigned short hi[4], lo[4];
    #pragma unroll
    for (int r = 0; r < 4; r++){
      hi[r] = f2bf(e[r]);
      lo[r] = f2bf(e[r] - bf2f(hi[r]));
    }
    *(ushort4*)&E2[(size_t)row*1024 + j4]       = make_ushort4(hi[0],hi[1],hi[2],hi[3]);
    *(ushort4*)&E2[(size_t)row*1024 + 512 + j4] = make_ushort4(lo[0],lo[1],lo[2],lo[3]);
  } else {
    int gid = (bid - 1280) * 256 + tid;       // 256 rows * 128 j4-chunks
    int row = gid >> 7, j4 = (gid & 127) << 2;
    float4 v = *(const float4*)&x[(size_t)row*DIN + j4];
    float e[4] = {v.x, v.y, v.z, v.w};
    unsigned short hi[4], lo[4];
    #pragma unroll
    for (int r = 0; r < 4; r++){
      hi[r] = f2bf(e[r]);
      lo[r] = f2bf(e[r] - bf2f(hi[r]));
    }
    *(ushort4*)&x2[(size_t)row*1024 + j4]       = make_ushort4(hi[0],hi[1],hi[2],hi[3]);
    *(ushort4*)&x2[(size_t)row*1024 + 512 + j4] = make_ushort4(lo[0],lo[1],lo[2],lo[3]);
  }
}

// ---------------- M2 = split-bf16 of (Kx .* (E E^T) + delta_{oo'} Kh) ----------------
// LDS-staged MFMA GEMM, BK=64, tile 128m x 64n, grid (40 n, 20 m), 256 thr (4 waves;
// wave w = 32 m-rows x 64 n). Same MAC order as R11/R13 -> bitwise-identical M2.
// Staging via global_load_lds w=16 with XOR-swizzled source chunks (T2; rule #21).
__global__ __launch_bounds__(256) void k_gemm_M(
    const unsigned short* __restrict__ E2, const float* __restrict__ Kx,
    const float* __restrict__ Kh, unsigned short* __restrict__ M2)
{
  __shared__ __align__(16) unsigned short As[128*64];   // 16 KB, row stride 64 elems
  __shared__ __align__(16) unsigned short Bs[64*64];    // 8 KB
  const int tid = threadIdx.x;
  const int w = tid >> 6, l = tid & 63;
  const int ln = l & 15, kq = l >> 4;
  const int m0 = blockIdx.y << 7, n0 = blockIdx.x << 6;

  // staging: per call c, thread covers row (c*32 + tid>>3), col-chunk tid&7;
  // source chunk = (tid&7) ^ (row&7)  [swizzle involution]
  const int srow = tid >> 3;                 // 0..31
  const int scc  = (tid & 7) ^ (srow & 7);
  const unsigned short* gA = E2 + (size_t)(m0 + srow)*1024 + scc*8;
  const unsigned short* gB = E2 + (size_t)(n0 + srow)*1024 + scc*8;
  // wave-uniform LDS base: wave w covers rows w*8.. per call -> offset w*512 elems
  unsigned short* lA = As + w*512;
  unsigned short* lB = Bs + w*512;

  f32x4 acc[2][4];
  #pragma unroll
  for (int i = 0; i < 2; i++)
    #pragma unroll
    for (int j = 0; j < 4; j++)
      acc[i][j] = (f32x4){0.f, 0.f, 0.f, 0.f};

  const int xs = ln & 7;   // read-side swizzle key (frag row&7 == ln&7)

  for (int t = 0; t < 24; ++t){
    const int p = t >> 3, k8 = t & 7;
    const int oa = ((p == 2) ? 512 : 0) + (k8 << 6);
    const int ob = ((p == 1) ? 512 : 0) + (k8 << 6);
    #pragma unroll
    for (int c = 0; c < 4; c++)
      gload16(gA + (size_t)c*32*1024 + oa, lA + c*2048);
    #pragma unroll
    for (int c = 0; c < 2; c++)
      gload16(gB + (size_t)c*32*1024 + ob, lB + c*2048);
    __syncthreads();   // drains vmcnt (gload_lds) before LDS reads

    #pragma unroll
    for (int kk = 0; kk < 2; kk++){
      const int kc = kq + (kk << 2);          // 8-elem chunk index 0..7
      const int co = (kc ^ xs) << 3;          // swizzled elem offset within row
      s16x8 af[2], bf[4];
      #pragma unroll
      for (int f = 0; f < 2; f++)
        af[f] = *(const s16x8*)(As + ((w<<5) + (f<<4) + ln)*64 + co);
      #pragma unroll
      for (int f = 0; f < 4; f++)
        bf[f] = *(const s16x8*)(Bs + ((f<<4) + ln)*64 + co);
      #pragma unroll
      for (int fi = 0; fi < 2; fi++)
        #pragma unroll
        for (int fj = 0; fj < 4; fj++)
          acc[fi][fj] = __builtin_amdgcn_mfma_f32_16x16x32_bf16(
              af[fi], bf[fj], acc[fi][fj], 0, 0, 0);
    }
    __syncthreads();   // LDS reuse next step
  }

  // epilogue: v = Kx*acc (+ Kh on o-diagonal); split-bf16 via HW cvt_pk (RNE)
  const int mb = m0 + (w << 5);
  int bmv[2][4], omv[2][4], bnv[4], onv[4];
  #pragma unroll
  for (int f = 0; f < 4; f++){
    int n = n0 + f*16 + ln; bnv[f] = n / 10; onv[f] = n - bnv[f]*10;
  }
  #pragma unroll
  for (int f = 0; f < 2; f++)
    #pragma unroll
    for (int r = 0; r < 4; r++){
      int m = mb + f*16 + kq*4 + r;
      bmv[f][r] = m / 10; omv[f][r] = m - bmv[f][r]*10;
    }
  #pragma unroll
  for (int fi = 0; fi < 2; fi++)
    #pragma unroll
    for (int r = 0; r < 4; r++){
      const int m = mb + fi*16 + kq*4 + r;
      float v[4];
      #pragma unroll
      for (int fj = 0; fj < 4; fj++){
        float vv = Kx[(size_t)bmv[fi][r]*BB + bnv[fj]] * acc[fi][fj][r];
        if (omv[fi][r] == onv[fj]) vv += Kh[(size_t)bmv[fi][r]*BB + bnv[fj]];
        v[fj] = vv;
      }
      #pragma unroll
      for (int p2 = 0; p2 < 2; p2++){
        const float v0 = v[2*p2], v1 = v[2*p2+1];
        const unsigned ph = cvt_pk_bf16(v0, v1);
        const float h0 = __uint_as_float(ph << 16);
        const float h1 = __uint_as_float(ph & 0xFFFF0000u);
        const unsigned pl = cvt_pk_bf16(v0 - h0, v1 - h1);
        const int na = n0 + (2*p2)*16 + ln, nb = na + 16;
        M2[(size_t)m*5120 + na]        = (unsigned short)ph;
        M2[(size_t)m*5120 + nb]        = (unsigned short)(ph >> 16);
        M2[(size_t)m*5120 + 2560 + na] = (unsigned short)pl;
        M2[(size_t)m*5120 + 2560 + nb] = (unsigned short)(pl >> 16);
      }
    }
}

// ---------------- T[s] = (x @ eps_W1[s] + eps_b1[s]) * G  via split-bf16 MFMA ----------------
// grid (8 n-tiles, 32 samples) x 512 thr (8 waves). Wave w owns m-frags {2w, 2w+1}.
// B (eW1 cols) split hi/lo on the fly with HW cvt_pk.
__global__ __launch_bounds__(512) void k_gemm_T(
    const unsigned short* __restrict__ x2, const float* __restrict__ eW1,
    const float* __restrict__ eb1, const float* __restrict__ G,
    float* __restrict__ T)
{
  const int tid = threadIdx.x;
  const int w = tid >> 6, l = tid & 63;
  const int ln = l & 15, kq = l >> 4;
  const int n0 = blockIdx.x << 6;
  const int s  = blockIdx.y;
  const float* Wb = eW1 + (size_t)s * DIN * HD;

  const unsigned short* pa[2];
  #pragma unroll
  for (int f = 0; f < 2; f++)
    pa[f] = x2 + (size_t)(16*(2*w + f) + ln) * 1024 + kq * 8;

  f32x4 acc[2][4];
  #pragma unroll
  for (int i = 0; i < 2; i++)
    #pragma unroll
    for (int j = 0; j < 4; j++)
      acc[i][j] = (f32x4){0.f, 0.f, 0.f, 0.f};

  #pragma unroll 2
  for (int k0 = 0; k0 < DIN; k0 += 32){
    float wv[4][8];
    const float* wp = Wb + (size_t)(k0 + kq*8)*HD + n0 + ln;
    #pragma unroll
    for (int i = 0; i < 8; i++)
      #pragma unroll
      for (int f = 0; f < 4; f++)
        wv[f][i] = wp[(size_t)i*HD + 16*f];

    s16x8 ahi[2], alo[2], bhi[4], blo[4];
    #pragma unroll
    for (int f = 0; f < 2; f++){
      ahi[f] = *(const s16x8*)(pa[f] + k0);
      alo[f] = *(const s16x8*)(pa[f] + 512 + k0);
    }
    #pragma unroll
    for (int f = 0; f < 4; f++){
      u32x4 bh, bl;
      #pragma unroll
      for (int i = 0; i < 4; i++){
        const float v0 = wv[f][2*i], v1 = wv[f][2*i+1];
        const unsigned ph = cvt_pk_bf16(v0, v1);
        bh[i] = ph;
        const float h0 = __uint_as_float(ph << 16);
        const float h1 = __uint_as_float(ph & 0xFFFF0000u);
        bl[i] = cvt_pk_bf16(v0 - h0, v1 - h1);
      }
      bhi[f] = __builtin_bit_cast(s16x8, bh);
      blo[f] = __builtin_bit_cast(s16x8, bl);
    }
    #pragma unroll
    for (int fi = 0; fi < 2; fi++)
      #pragma unroll
      for (int fj = 0; fj < 4; fj++){
        acc[fi][fj] = __builtin_amdgcn_mfma_f32_16x16x32_bf16(ahi[fi], bhi[fj], acc[fi][fj], 0,0,0);
        acc[fi][fj] = __builtin_amdgcn_mfma_f32_16x16x32_bf16(ahi[fi], blo[fj], acc[fi][fj], 0,0,0);
        acc[fi][fj] = __builtin_amdgcn_mfma_f32_16x16x32_bf16(alo[fi], bhi[fj], acc[fi][fj], 0,0,0);
      }
  }

  #pragma unroll
  for (int fj = 0; fj < 4; fj++){
    const int n = n0 + 16*fj + ln;
    const float eb = eb1[(size_t)s*HD + n];
    #pragma unroll
    for (int fi = 0; fi < 2; fi++)
      #pragma unroll
      for (int q = 0; q < 4; q++){
        const int m = 16*(2*w + fi) + kq*4 + q;
        T[((size_t)s*BB + m)*HD + n] = (acc[fi][fj][q] + eb) * G[(size_t)m*HD + n];
      }
  }
}

// ---------------- bvec (+ out0 for s==0 blocks) ----------------
__global__ __launch_bounds__(256) void k_bvec(
    const float* __restrict__ T, const float* __restrict__ W2,
    const float* __restrict__ h, const float* __restrict__ eW2,
    const float* __restrict__ eb2, const float* __restrict__ b2,
    float* __restrict__ bvec, float* __restrict__ out0, float* __restrict__ rr0_part)
{
  __shared__ __align__(16) float W2t[10][516];
  __shared__ __align__(16) float E2t[10][516];
  __shared__ float wl[4];
  const int tid = threadIdx.x, bid = blockIdx.x;
  const int s = bid / 10;
  const int idx = (bid % 10) * 256 + tid;
  const int b = idx / 10, o = idx - b*10;
  const float* e2 = eW2 + (size_t)s * HD * DOUT;
  for (int i = tid; i < HD*DOUT; i += 256){
    int k = i / 10, oo = i - k*10;
    W2t[oo][k] = W2[i];
    E2t[oo][k] = e2[i];
  }
  __syncthreads();
  const float* Tr = T + ((size_t)s*BB + b) * HD;
  const float* hr = h + (size_t)b * HD;
  const bool do0 = (bid < 10);
  float acc = eb2[s*DOUT + o];
  float a0 = 0.f;
  #pragma unroll 4
  for (int k4 = 0; k4 < HD/4; k4++){
    float4 t4 = *(const float4*)(Tr + (k4<<2));
    float4 h4 = *(const float4*)(hr + (k4<<2));
    float4 w4 = *(const float4*)&W2t[o][k4<<2];
    float4 q4 = *(const float4*)&E2t[o][k4<<2];
    acc += t4.x*w4.x + t4.y*w4.y + t4.z*w4.z + t4.w*w4.w
         + h4.x*q4.x + h4.y*q4.y + h4.z*q4.z + h4.w*q4.w;
    if (do0) a0 += h4.x*w4.x + h4.y*w4.y + h4.z*w4.z + h4.w*w4.w;
  }
  bvec[(size_t)s*NIDX + idx] = acc;
  if (do0) out0[idx] = a0 + b2[o];
  float v = wave_red(acc * acc);
  if ((tid & 63) == 0) wl[tid >> 6] = v;
  __syncthreads();
  if (tid == 0) rr0_part[bid] = wl[0]+wl[1]+wl[2]+wl[3];
}

// ---------------- CG init ----------------
__global__ __launch_bounds__(256) void k_init(
    const float* __restrict__ bvec, const float* __restrict__ rr0_part,
    float* __restrict__ r, float* __restrict__ p, float* __restrict__ a,
    float* __restrict__ basis, float* __restrict__ rr_arr,
    unsigned short* __restrict__ ps2)
{
  int gid = blockIdx.x * 256 + threadIdx.x;
  int s = gid / NIDX, idx = gid - s * NIDX;
  float rr0 = 0.f;
  #pragma unroll
  for (int i = 0; i < 10; i++) rr0 += rr0_part[s*10 + i];
  float bv = bvec[gid];
  r[gid] = bv; p[gid] = bv; a[gid] = 0.f;
  basis[gid] = bv / (sqrtf(rr0) + CG_EPS);
  unsigned short hh = f2bf(bv);
  ps2[(size_t)s*5120 + idx]        = hh;
  ps2[(size_t)s*5120 + 2560 + idx] = f2bf(bv - bf2f(hh));
  if (threadIdx.x == 0) rr_arr[s] = rr0;
}

// ---------------- matvec: Ap_part[kh][s][r] via split-bf16 MFMA ----------------
// grid (160 row-blocks of 16, 4 K-quarters), 256 thr (4 waves, wave = 160-col slice).
__global__ __launch_bounds__(256) void k_matvec(
    const unsigned short* __restrict__ M2, const unsigned short* __restrict__ p2,
    float* __restrict__ Ap_part)
{
  __shared__ float red[4][16][33];
  const int tid = threadIdx.x;
  const int w = tid >> 6, l = tid & 63;
  const int ln = l & 15, kq = l >> 4;
  const int R0 = blockIdx.x << 4;
  const int kh = blockIdx.y;                 // 0..3
  const int c0 = kh*640 + w*160;

  const unsigned short* a0p = M2 + (size_t)(R0 + ln)*5120 + c0 + kq*8;
  const unsigned short* q0  = p2 + (size_t)ln*5120        + c0 + kq*8;
  const unsigned short* q1  = p2 + (size_t)(16 + ln)*5120 + c0 + kq*8;

  f32x4 acc[2];
  acc[0] = (f32x4){0.f,0.f,0.f,0.f};
  acc[1] = (f32x4){0.f,0.f,0.f,0.f};

  #pragma unroll
  for (int ch = 0; ch < 5; ch++){
    const int o = ch * 32;
    s16x8 bh0 = *(const s16x8*)(q0 + o);
    s16x8 bl0 = *(const s16x8*)(q0 + 2560 + o);
    s16x8 bh1 = *(const s16x8*)(q1 + o);
    s16x8 bl1 = *(const s16x8*)(q1 + 2560 + o);
    s16x8 a0h = *(const s16x8*)(a0p + o);
    s16x8 a0l = *(const s16x8*)(a0p + 2560 + o);
    acc[0] = __builtin_amdgcn_mfma_f32_16x16x32_bf16(a0h, bh0, acc[0], 0,0,0);
    acc[1] = __builtin_amdgcn_mfma_f32_16x16x32_bf16(a0h, bh1, acc[1], 0,0,0);
    acc[0] = __builtin_amdgcn_mfma_f32_16x16x32_bf16(a0h, bl0, acc[0], 0,0,0);
    acc[1] = __builtin_amdgcn_mfma_f32_16x16x32_bf16(a0h, bl1, acc[1], 0,0,0);
    acc[0] = __builtin_amdgcn_mfma_f32_16x16x32_bf16(a0l, bh0, acc[0], 0,0,0);
    acc[1] = __builtin_amdgcn_mfma_f32_16x16x32_bf16(a0l, bh1, acc[1], 0,0,0);
  }

  #pragma unroll
  for (int g = 0; g < 2; g++)
    #pragma unroll
    for (int q = 0; q < 4; q++)
      red[w][kq*4 + q][16*g + ln] = acc[g][q];
  __syncthreads();
  #pragma unroll
  for (int j = 0; j < 2; j++){
    const int idx = tid + (j << 8);
    const int r = idx & 15, s = idx >> 4;
    float v = red[0][r][s] + red[1][r][s] + red[2][r][s] + red[3][r][s];
    Ap_part[((size_t)kh*NS + s)*NIDX + R0 + r] = v;
  }
}

// ---------------- fused CG update (pAp, alpha, a/r, reortho, beta, p, basis, ps2) ----------------
// 32 blocks x 512 thr (8 waves); thread owns idx = tid + 512c, c<5
__global__ __launch_bounds__(512) void k_cg(
    const float* __restrict__ Ap_part, float* __restrict__ rr_arr, int k, int last,
    float* __restrict__ pv, unsigned short* __restrict__ ps2,
    unsigned short* __restrict__ as2,
    float* __restrict__ av, float* __restrict__ rv, float* __restrict__ basis)
{
  __shared__ float wl[8];
  __shared__ float red[8][10];
  __shared__ float cbr[10];
  const int s = blockIdx.x, tid = threadIdx.x;
  const int w = tid >> 6;
  const size_t base = (size_t)s * NIDX;
  const float rr = rr_arr[s];

  float ap[5], pvv[5];
  #pragma unroll
  for (int c = 0; c < 5; c++){
    const int idx = tid + (c << 9);
    float apv = 0.f;
    #pragma unroll
    for (int kc = 0; kc < 4; kc++)
      apv += Ap_part[((size_t)kc*NS + s)*NIDX + idx];
    ap[c]  = apv;
    pvv[c] = pv[base + idx];
  }
  float v = 0.f;
  #pragma unroll
  for (int c = 0; c < 5; c++) v += pvv[c] * ap[c];
  v = wave_red(v);
  if ((tid & 63) == 0) wl[w] = v;
  __syncthreads();
  const float pAp = wl[0]+wl[1]+wl[2]+wl[3]+wl[4]+wl[5]+wl[6]+wl[7];
  const float alpha = rr / (pAp + CG_EPS);

  float rn[5];
  #pragma unroll
  for (int c = 0; c < 5; c++){
    const int idx = tid + (c << 9);
    const float an = av[base + idx] + alpha * pvv[c];
    av[base + idx] = an;
    rn[c] = rv[base + idx] - alpha * ap[c];
    if (last){
      unsigned short hh = f2bf(an);
      as2[(size_t)s*5120 + idx]        = hh;
      as2[(size_t)s*5120 + 2560 + idx] = f2bf(an - bf2f(hh));
    }
  }

  for (int j = 0; j <= k; j++){
    float cv = 0.f;
    const float* brow = basis + (size_t)j * (NS*NIDX) + base;
    #pragma unroll
    for (int c = 0; c < 5; c++) cv += brow[tid + (c << 9)] * rn[c];
    cv = wave_red(cv);
    if ((tid & 63) == 0) red[w][j] = cv;
  }
  __syncthreads();
  if (tid <= k){
    float cs = 0.f;
    #pragma unroll
    for (int ww = 0; ww < 8; ww++) cs += red[ww][tid];
    cbr[tid] = cs;
  }
  __syncthreads();

  for (int j = 0; j <= k; j++){
    const float cc = cbr[j];
    const float* brow = basis + (size_t)j * (NS*NIDX) + base;
    #pragma unroll
    for (int c = 0; c < 5; c++) rn[c] -= brow[tid + (c << 9)] * cc;
  }

  float rr2 = 0.f;
  #pragma unroll
  for (int c = 0; c < 5; c++) rr2 += rn[c]*rn[c];
  rr2 = wave_red(rr2);
  __syncthreads();
  if ((tid & 63) == 0) wl[w] = rr2;
  __syncthreads();
  const float rrn = wl[0]+wl[1]+wl[2]+wl[3]+wl[4]+wl[5]+wl[6]+wl[7];
  const float beta = rrn / (rr + CG_EPS);
  const float inv  = 1.0f / (sqrtf(rrn) + CG_EPS);

  float* bnew = basis + (size_t)(k+1) * (NS*NIDX) + base;
  #pragma unroll
  for (int c = 0; c < 5; c++){
    const int idx = tid + (c << 9);
    const float pnew = rn[c] + beta * pvv[c];
    rv[base + idx] = rn[c];
    pv[base + idx] = pnew;
    bnew[idx] = rn[c] * inv;
    unsigned short hh = f2bf(pnew);
    ps2[(size_t)s*5120 + idx]        = hh;
    ps2[(size_t)s*5120 + 2560 + idx] = f2bf(pnew - bf2f(hh));
  }
  if (tid == 0) rr_arr[s] = rrn;
}

// ---------------- final: preds = out0 + si*b + (sk-si)*(M a) ----------------
__global__ __launch_bounds__(256) void k_final(
    const float* __restrict__ out0, const float* __restrict__ bvec,
    const float* __restrict__ Ap_part, const float* __restrict__ lp,
    const float* __restrict__ lsi, float* __restrict__ out)
{
  int gid = blockIdx.x * 256 + threadIdx.x;
  int s = gid / NIDX, idx = gid - s * NIDX;
  float sk = expf(-0.5f * lp[0]);
  float si = expf(lsi[0]);
  float ma = 0.f;
  #pragma unroll
  for (int kc = 0; kc < 4; kc++) ma += Ap_part[(size_t)kc*NS*NIDX + gid];
  out[gid] = out0[idx] + si * bvec[gid] + (sk - si) * ma;
}

// ---------------- launch ----------------
extern "C" void kernel_launch(void* const* d_in, const int* in_sizes, int n_in,
                              void* d_out, int out_size, void* d_ws, size_t ws_size,
                              hipStream_t stream)
{
  const float* x   = (const float*)d_in[0];
  const float* W1  = (const float*)d_in[1];
  const float* b1  = (const float*)d_in[2];
  const float* W2  = (const float*)d_in[3];
  const float* b2  = (const float*)d_in[4];
  const float* eW1 = (const float*)d_in[5];
  const float* eb1 = (const float*)d_in[6];
  const float* eW2 = (const float*)d_in[7];
  const float* eb2 = (const float*)d_in[8];
  const float* lp  = (const float*)d_in[9];
  const float* lsi = (const float*)d_in[10];
  float* outp = (float*)d_out;

  float* ws = (float*)d_ws;
  float* h        = ws;                       // 131072
  float* G        = h        + 131072;        // 131072
  float* Kx       = G        + 131072;        // 65536
  float* Kh       = Kx       + 65536;         // 65536
  float* E2f      = Kh       + 65536;         // 1310720 (2560x1024 bf16 hi|lo)
  float* x2f      = E2f      + 1310720;       // 131072  (256x1024 bf16 hi|lo)
  float* M2f      = x2f      + 131072;        // 6553600 (2560x5120 bf16 hi|lo); T aliases
  float* out0     = M2f      + 6553600;       // 2560
  float* bvec     = out0     + 2560;          // 81920
  float* rv       = bvec     + 81920;         // 81920
  float* pv       = rv       + 81920;         // 81920
  float* av       = pv       + 81920;         // 81920
  float* basis    = av       + 81920;         // 901120 (11*81920)
  float* Ap_part  = basis    + 901120;        // 327680 (4*32*2560)
  float* ps2f     = Ap_part  + 327680;        // 81920 floats (32x5120 ushorts hi|lo)
  float* as2f     = ps2f     + 81920;         // 81920 floats
  float* rr0_part = as2f     + 81920;         // 320
  float* rr_arr   = rr0_part + 320;           // 32
  // total ~10.11M floats = ~40.4 MB

  unsigned short* E2  = (unsigned short*)E2f;
  unsigned short* x2  = (unsigned short*)x2f;
  unsigned short* M2  = (unsigned short*)M2f;
  unsigned short* ps2 = (unsigned short*)ps2f;
  unsigned short* as2 = (unsigned short*)as2f;
  float* T = M2f;   // alias: T (4,194,304 floats) dead before M2 is built

  k_gemm_z   <<<dim3(8,4),   256, 0, stream>>>(x, W1, b1, h, G);
  k_buildEx  <<<1408,        256, 0, stream>>>(G, W2, x, E2, x2);
  k_gemm_kxkh<<<dim3(4,4,2), 256, 0, stream>>>(x, h, Kx, Kh);
  k_gemm_T   <<<dim3(8,32),  512, 0, stream>>>(x2, eW1, eb1, G, T);
  k_bvec     <<<320,         256, 0, stream>>>(T, W2, h, eW2, eb2, b2, bvec, out0, rr0_part);
  k_gemm_M   <<<dim3(40,20), 256, 0, stream>>>(E2, Kx, Kh, M2);  // overwrites T (dead)
  k_init     <<<320,         256, 0, stream>>>(bvec, rr0_part, rv, pv, av, basis, rr_arr, ps2);

  for (int k = 0; k < MAXIT; k++){
    k_matvec<<<dim3(160,4), 256, 0, stream>>>(M2, ps2, Ap_part);
    k_cg    <<<NS,          512, 0, stream>>>(Ap_part, rr_arr, k, (k == MAXIT-1),
                                              pv, ps2, as2, av, rv, basis);
  }

  k_matvec<<<dim3(160,4), 256, 0, stream>>>(M2, as2, Ap_part);
  k_final <<<320,         256, 0, stream>>>(out0, bvec, Ap_part, lp, lsi, outp);
}

// Round 15
// 368.409 us; speedup vs baseline: 1.1232x; 1.0162x over previous
//
#include <hip/hip_runtime.h>
#include <math.h>

#define BB    256      // batch
#define DIN   512
#define HD    512
#define DOUT  10
#define NS    32       // samples
#define NIDX  2560     // BB*DOUT
#define MAXIT 10
#define CG_EPS 1e-12f

typedef __attribute__((ext_vector_type(8))) short s16x8;     // 8 bf16 (4 VGPRs)
typedef __attribute__((ext_vector_type(4))) float f32x4;     // 4 fp32 acc
typedef __attribute__((ext_vector_type(4))) unsigned u32x4;  // 4 dwords

// ---------------- helpers ----------------
__device__ __forceinline__ float wave_red(float v){
  #pragma unroll
  for (int off = 32; off > 0; off >>= 1) v += __shfl_down(v, off, 64);
  return v;  // lane 0 holds total
}
__device__ __forceinline__ unsigned short f2bf(float f){
  unsigned u = __float_as_uint(f);
  return (unsigned short)((u + 0x7FFFu + ((u >> 16) & 1u)) >> 16);
}
__device__ __forceinline__ float bf2f(unsigned short h){
  return __uint_as_float((unsigned)h << 16);
}
// HW packed cvt (RNE, same bits as f2bf): dst.lo = bf16(a), dst.hi = bf16(b)
__device__ __forceinline__ unsigned cvt_pk_bf16(float a, float b){
  unsigned r;
  asm("v_cvt_pk_bf16_f32 %0, %1, %2" : "=v"(r) : "v"(a), "v"(b));
  return r;
}

typedef const __attribute__((address_space(1))) unsigned short gus_t;
typedef __attribute__((address_space(3))) unsigned short lus_t;
__device__ __forceinline__ void gload16(const unsigned short* g, unsigned short* l){
  // async global->LDS, 16B/lane; LDS dest = wave-uniform base + lane*16
  __builtin_amdgcn_global_load_lds((gus_t*)g, (lus_t*)l, 16, 0, 0);
}

// ---------------- x2 = [xhi | xlo] bf16 ----------------
__global__ __launch_bounds__(256) void k_buildx(
    const float* __restrict__ x, unsigned short* __restrict__ x2)
{
  int gid = blockIdx.x * 256 + threadIdx.x;   // 256 rows * 128 j4-chunks
  int row = gid >> 7, j4 = (gid & 127) << 2;
  float4 v = *(const float4*)&x[(size_t)row*DIN + j4];
  float e[4] = {v.x, v.y, v.z, v.w};
  unsigned short hi[4], lo[4];
  #pragma unroll
  for (int r = 0; r < 4; r++){
    hi[r] = f2bf(e[r]);
    lo[r] = f2bf(e[r] - bf2f(hi[r]));
  }
  *(ushort4*)&x2[(size_t)row*1024 + j4]       = make_ushort4(hi[0],hi[1],hi[2],hi[3]);
  *(ushort4*)&x2[(size_t)row*1024 + 512 + j4] = make_ushort4(lo[0],lo[1],lo[2],lo[3]);
}

// ---------------- gemm_T + z fused ----------------
// grid (8 n-tiles, 33) x 512 thr (8 waves). s<32: T_raw[s] = x @ eW1[s] + eb1[s]
// (G applied later in k_bvec). s==32: z = x @ W1 + b1 -> h=tanh(z), G=1-h^2, h2=split(h).
// Wave w owns m-frags {2w, 2w+1}; B cols split hi/lo on the fly with HW cvt_pk.
__global__ __launch_bounds__(512) void k_gemm_T(
    const unsigned short* __restrict__ x2, const float* __restrict__ eW1,
    const float* __restrict__ eb1, const float* __restrict__ W1,
    const float* __restrict__ b1, float* __restrict__ T,
    float* __restrict__ h, float* __restrict__ G, unsigned short* __restrict__ h2)
{
  const int tid = threadIdx.x;
  const int w = tid >> 6, l = tid & 63;
  const int ln = l & 15, kq = l >> 4;
  const int n0 = blockIdx.x << 6;
  const int s  = blockIdx.y;                  // 0..32
  const bool isz = (s == NS);
  const float* Wb = isz ? W1 : (eW1 + (size_t)s * DIN * HD);

  const unsigned short* pa[2];
  #pragma unroll
  for (int f = 0; f < 2; f++)
    pa[f] = x2 + (size_t)(16*(2*w + f) + ln) * 1024 + kq * 8;

  f32x4 acc[2][4];
  #pragma unroll
  for (int i = 0; i < 2; i++)
    #pragma unroll
    for (int j = 0; j < 4; j++)
      acc[i][j] = (f32x4){0.f, 0.f, 0.f, 0.f};

  #pragma unroll 2
  for (int k0 = 0; k0 < DIN; k0 += 32){
    float wv[4][8];
    const float* wp = Wb + (size_t)(k0 + kq*8)*HD + n0 + ln;
    #pragma unroll
    for (int i = 0; i < 8; i++)
      #pragma unroll
      for (int f = 0; f < 4; f++)
        wv[f][i] = wp[(size_t)i*HD + 16*f];

    s16x8 ahi[2], alo[2], bhi[4], blo[4];
    #pragma unroll
    for (int f = 0; f < 2; f++){
      ahi[f] = *(const s16x8*)(pa[f] + k0);
      alo[f] = *(const s16x8*)(pa[f] + 512 + k0);
    }
    #pragma unroll
    for (int f = 0; f < 4; f++){
      u32x4 bh, bl;
      #pragma unroll
      for (int i = 0; i < 4; i++){
        const float v0 = wv[f][2*i], v1 = wv[f][2*i+1];
        const unsigned ph = cvt_pk_bf16(v0, v1);
        bh[i] = ph;
        const float h0 = __uint_as_float(ph << 16);
        const float h1 = __uint_as_float(ph & 0xFFFF0000u);
        bl[i] = cvt_pk_bf16(v0 - h0, v1 - h1);
      }
      bhi[f] = __builtin_bit_cast(s16x8, bh);
      blo[f] = __builtin_bit_cast(s16x8, bl);
    }
    #pragma unroll
    for (int fi = 0; fi < 2; fi++)
      #pragma unroll
      for (int fj = 0; fj < 4; fj++){
        acc[fi][fj] = __builtin_amdgcn_mfma_f32_16x16x32_bf16(ahi[fi], bhi[fj], acc[fi][fj], 0,0,0);
        acc[fi][fj] = __builtin_amdgcn_mfma_f32_16x16x32_bf16(ahi[fi], blo[fj], acc[fi][fj], 0,0,0);
        acc[fi][fj] = __builtin_amdgcn_mfma_f32_16x16x32_bf16(alo[fi], bhi[fj], acc[fi][fj], 0,0,0);
      }
  }

  if (!isz){
    #pragma unroll
    for (int fj = 0; fj < 4; fj++){
      const int n = n0 + 16*fj + ln;
      const float eb = eb1[(size_t)s*HD + n];
      #pragma unroll
      for (int fi = 0; fi < 2; fi++)
        #pragma unroll
        for (int q = 0; q < 4; q++){
          const int m = 16*(2*w + fi) + kq*4 + q;
          T[((size_t)s*BB + m)*HD + n] = acc[fi][fj][q] + eb;
        }
    }
  } else {
    #pragma unroll
    for (int fj = 0; fj < 4; fj++){
      const int n = n0 + 16*fj + ln;
      const float eb = b1[n];
      #pragma unroll
      for (int fi = 0; fi < 2; fi++)
        #pragma unroll
        for (int q = 0; q < 4; q++){
          const int m = 16*(2*w + fi) + kq*4 + q;
          const float t = tanhf(acc[fi][fj][q] + eb);
          const float g = 1.0f - t*t;
          h[(size_t)m*HD + n] = t;
          G[(size_t)m*HD + n] = g;
          unsigned short hh = f2bf(t);
          h2[(size_t)m*1024 + n]       = hh;
          h2[(size_t)m*1024 + 512 + n] = f2bf(t - bf2f(hh));
        }
    }
  }
}

// ---------------- E2 = [Ehi | Elo] bf16, E[(b,o)][j] = G[b][j]*W2[j][o] ----------------
__global__ __launch_bounds__(256) void k_buildE(
    const float* __restrict__ G, const float* __restrict__ W2,
    unsigned short* __restrict__ E2)
{
  int gid = blockIdx.x * 256 + threadIdx.x;   // 2560 rows * 128 j4-chunks
  int row = gid >> 7, j4 = (gid & 127) << 2;
  int b = row / 10, o = row - b * 10;
  float4 g = *(const float4*)&G[(size_t)b*HD + j4];
  float e[4] = { g.x * W2[(j4+0)*DOUT + o], g.y * W2[(j4+1)*DOUT + o],
                 g.z * W2[(j4+2)*DOUT + o], g.w * W2[(j4+3)*DOUT + o] };
  unsigned short hi[4], lo[4];
  #pragma unroll
  for (int r = 0; r < 4; r++){
    hi[r] = f2bf(e[r]);
    lo[r] = f2bf(e[r] - bf2f(hi[r]));
  }
  *(ushort4*)&E2[(size_t)row*1024 + j4]       = make_ushort4(hi[0],hi[1],hi[2],hi[3]);
  *(ushort4*)&E2[(size_t)row*1024 + 512 + j4] = make_ushort4(lo[0],lo[1],lo[2],lo[3]);
}

// ---------------- Kx/Kh partials: K-split x4, fp32 LDS GEMM ----------------
// grid (4,4,8): z = which*4 + kc; A = which? h : x; K window [kc*128, kc*128+128)
__global__ __launch_bounds__(256) void k_kxkh(
    const float* __restrict__ x, const float* __restrict__ h,
    float* __restrict__ Kp)
{
  __shared__ __align__(16) float Al[16][68];
  __shared__ __align__(16) float Bl[16][68];
  const int tid = threadIdx.x;
  const int which = blockIdx.z >> 2, kc = blockIdx.z & 3;
  const float* A = which ? h : x;
  float* C = Kp + (size_t)blockIdx.z * 65536;
  const int m0 = blockIdx.y * 64, n0 = blockIdx.x * 64;
  const int tx = tid & 15, ty = tid >> 4;
  const int kbase = kc << 7;
  float acc[4][4] = {};
  for (int k0 = kbase; k0 < kbase + 128; k0 += 16){
    {
      int m = tid >> 2, kk = (tid & 3) << 2;
      float4 a = *(const float4*)(A + (size_t)(m0+m)*DIN + k0 + kk);
      Al[kk+0][m]=a.x; Al[kk+1][m]=a.y; Al[kk+2][m]=a.z; Al[kk+3][m]=a.w;
      float4 b = *(const float4*)(A + (size_t)(n0+m)*DIN + k0 + kk);
      Bl[kk+0][m]=b.x; Bl[kk+1][m]=b.y; Bl[kk+2][m]=b.z; Bl[kk+3][m]=b.w;
    }
    __syncthreads();
    #pragma unroll
    for (int kk = 0; kk < 16; kk++){
      float4 av = *(const float4*)&Al[kk][ty<<2];
      float4 bv = *(const float4*)&Bl[kk][tx<<2];
      float aa[4]={av.x,av.y,av.z,av.w}, bb[4]={bv.x,bv.y,bv.z,bv.w};
      #pragma unroll
      for (int i=0;i<4;i++)
        #pragma unroll
        for (int j=0;j<4;j++) acc[i][j] += aa[i]*bb[j];
    }
    __syncthreads();
  }
  #pragma unroll
  for (int i=0;i<4;i++){
    int m = m0 + (ty<<2) + i;
    *(float4*)&C[(size_t)m*BB + n0 + (tx<<2)] =
        make_float4(acc[i][0], acc[i][1], acc[i][2], acc[i][3]);
  }
}

// ---------------- combine: Kx/Kh = sum of 4 K-partials + 1 ----------------
__global__ __launch_bounds__(256) void k_comb(
    const float* __restrict__ Kp, float* __restrict__ Kx, float* __restrict__ Kh)
{
  int gid = blockIdx.x * 256 + threadIdx.x;   // 131072
  int which = gid >> 16, idx = gid & 65535;
  const float* base = Kp + (size_t)which * 4 * 65536;
  float v = base[idx] + base[65536 + idx] + base[2*65536 + idx] + base[3*65536 + idx] + 1.0f;
  (which ? Kh : Kx)[idx] = v;
}

// ---------------- M2 = split-bf16 of (Kx .* (E E^T) + delta_{oo'} Kh) ----------------
// LDS-staged MFMA GEMM, BK=64, tile 128m x 64n, grid (40 n, 20 m), 256 thr (4 waves;
// wave w = 32 m-rows x 64 n). Staging via global_load_lds w=16, XOR-swizzled (T2).
__global__ __launch_bounds__(256) void k_gemm_M(
    const unsigned short* __restrict__ E2, const float* __restrict__ Kx,
    const float* __restrict__ Kh, unsigned short* __restrict__ M2)
{
  __shared__ __align__(16) unsigned short As[128*64];   // 16 KB, row stride 64 elems
  __shared__ __align__(16) unsigned short Bs[64*64];    // 8 KB
  const int tid = threadIdx.x;
  const int w = tid >> 6, l = tid & 63;
  const int ln = l & 15, kq = l >> 4;
  const int m0 = blockIdx.y << 7, n0 = blockIdx.x << 6;

  const int srow = tid >> 3;                 // 0..31
  const int scc  = (tid & 7) ^ (srow & 7);
  const unsigned short* gA = E2 + (size_t)(m0 + srow)*1024 + scc*8;
  const unsigned short* gB = E2 + (size_t)(n0 + srow)*1024 + scc*8;
  unsigned short* lA = As + w*512;
  unsigned short* lB = Bs + w*512;

  f32x4 acc[2][4];
  #pragma unroll
  for (int i = 0; i < 2; i++)
    #pragma unroll
    for (int j = 0; j < 4; j++)
      acc[i][j] = (f32x4){0.f, 0.f, 0.f, 0.f};

  const int xs = ln & 7;

  for (int t = 0; t < 24; ++t){
    const int p = t >> 3, k8 = t & 7;
    const int oa = ((p == 2) ? 512 : 0) + (k8 << 6);
    const int ob = ((p == 1) ? 512 : 0) + (k8 << 6);
    #pragma unroll
    for (int c = 0; c < 4; c++)
      gload16(gA + (size_t)c*32*1024 + oa, lA + c*2048);
    #pragma unroll
    for (int c = 0; c < 2; c++)
      gload16(gB + (size_t)c*32*1024 + ob, lB + c*2048);
    __syncthreads();

    #pragma unroll
    for (int kk = 0; kk < 2; kk++){
      const int kc = kq + (kk << 2);
      const int co = (kc ^ xs) << 3;
      s16x8 af[2], bf[4];
      #pragma unroll
      for (int f = 0; f < 2; f++)
        af[f] = *(const s16x8*)(As + ((w<<5) + (f<<4) + ln)*64 + co);
      #pragma unroll
      for (int f = 0; f < 4; f++)
        bf[f] = *(const s16x8*)(Bs + ((f<<4) + ln)*64 + co);
      #pragma unroll
      for (int fi = 0; fi < 2; fi++)
        #pragma unroll
        for (int fj = 0; fj < 4; fj++)
          acc[fi][fj] = __builtin_amdgcn_mfma_f32_16x16x32_bf16(
              af[fi], bf[fj], acc[fi][fj], 0, 0, 0);
    }
    __syncthreads();
  }

  const int mb = m0 + (w << 5);
  int bmv[2][4], omv[2][4], bnv[4], onv[4];
  #pragma unroll
  for (int f = 0; f < 4; f++){
    int n = n0 + f*16 + ln; bnv[f] = n / 10; onv[f] = n - bnv[f]*10;
  }
  #pragma unroll
  for (int f = 0; f < 2; f++)
    #pragma unroll
    for (int r = 0; r < 4; r++){
      int m = mb + f*16 + kq*4 + r;
      bmv[f][r] = m / 10; omv[f][r] = m - bmv[f][r]*10;
    }
  #pragma unroll
  for (int fi = 0; fi < 2; fi++)
    #pragma unroll
    for (int r = 0; r < 4; r++){
      const int m = mb + fi*16 + kq*4 + r;
      float v[4];
      #pragma unroll
      for (int fj = 0; fj < 4; fj++){
        float vv = Kx[(size_t)bmv[fi][r]*BB + bnv[fj]] * acc[fi][fj][r];
        if (omv[fi][r] == onv[fj]) vv += Kh[(size_t)bmv[fi][r]*BB + bnv[fj]];
        v[fj] = vv;
      }
      #pragma unroll
      for (int p2 = 0; p2 < 2; p2++){
        const float v0 = v[2*p2], v1 = v[2*p2+1];
        const unsigned ph = cvt_pk_bf16(v0, v1);
        const float h0 = __uint_as_float(ph << 16);
        const float h1 = __uint_as_float(ph & 0xFFFF0000u);
        const unsigned pl = cvt_pk_bf16(v0 - h0, v1 - h1);
        const int na = n0 + (2*p2)*16 + ln, nb = na + 16;
        M2[(size_t)m*5120 + na]        = (unsigned short)ph;
        M2[(size_t)m*5120 + nb]        = (unsigned short)(ph >> 16);
        M2[(size_t)m*5120 + 2560 + na] = (unsigned short)pl;
        M2[(size_t)m*5120 + 2560 + nb] = (unsigned short)(pl >> 16);
      }
    }
}

// ---------------- bvec (+ out0 for s==0 blocks); T is raw (G applied here) --------
__global__ __launch_bounds__(256) void k_bvec(
    const float* __restrict__ T, const float* __restrict__ W2,
    const float* __restrict__ h, const float* __restrict__ G,
    const float* __restrict__ eW2, const float* __restrict__ eb2,
    const float* __restrict__ b2,
    float* __restrict__ bvec, float* __restrict__ out0, float* __restrict__ rr0_part)
{
  __shared__ __align__(16) float W2t[10][516];
  __shared__ __align__(16) float E2t[10][516];
  __shared__ float wl[4];
  const int tid = threadIdx.x, bid = blockIdx.x;
  const int s = bid / 10;
  const int idx = (bid % 10) * 256 + tid;
  const int b = idx / 10, o = idx - b*10;
  const float* e2 = eW2 + (size_t)s * HD * DOUT;
  for (int i = tid; i < HD*DOUT; i += 256){
    int k = i / 10, oo = i - k*10;
    W2t[oo][k] = W2[i];
    E2t[oo][k] = e2[i];
  }
  __syncthreads();
  const float* Tr = T + ((size_t)s*BB + b) * HD;
  const float* hr = h + (size_t)b * HD;
  const float* Gr = G + (size_t)b * HD;
  const bool do0 = (bid < 10);
  float acc = eb2[s*DOUT + o];
  float a0 = 0.f;
  #pragma unroll 4
  for (int k4 = 0; k4 < HD/4; k4++){
    float4 t4 = *(const float4*)(Tr + (k4<<2));
    float4 h4 = *(const float4*)(hr + (k4<<2));
    float4 g4 = *(const float4*)(Gr + (k4<<2));
    float4 w4 = *(const float4*)&W2t[o][k4<<2];
    float4 q4 = *(const float4*)&E2t[o][k4<<2];
    acc += t4.x*g4.x*w4.x + t4.y*g4.y*w4.y + t4.z*g4.z*w4.z + t4.w*g4.w*w4.w
         + h4.x*q4.x + h4.y*q4.y + h4.z*q4.z + h4.w*q4.w;
    if (do0) a0 += h4.x*w4.x + h4.y*w4.y + h4.z*w4.z + h4.w*w4.w;
  }
  bvec[(size_t)s*NIDX + idx] = acc;
  if (do0) out0[idx] = a0 + b2[o];
  float v = wave_red(acc * acc);
  if ((tid & 63) == 0) wl[tid >> 6] = v;
  __syncthreads();
  if (tid == 0) rr0_part[bid] = wl[0]+wl[1]+wl[2]+wl[3];
}

// ---------------- CG init ----------------
__global__ __launch_bounds__(256) void k_init(
    const float* __restrict__ bvec, const float* __restrict__ rr0_part,
    float* __restrict__ r, float* __restrict__ p, float* __restrict__ a,
    float* __restrict__ basis, float* __restrict__ rr_arr,
    unsigned short* __restrict__ ps2)
{
  int gid = blockIdx.x * 256 + threadIdx.x;
  int s = gid / NIDX, idx = gid - s * NIDX;
  float rr0 = 0.f;
  #pragma unroll
  for (int i = 0; i < 10; i++) rr0 += rr0_part[s*10 + i];
  float bv = bvec[gid];
  r[gid] = bv; p[gid] = bv; a[gid] = 0.f;
  basis[gid] = bv / (sqrtf(rr0) + CG_EPS);
  unsigned short hh = f2bf(bv);
  ps2[(size_t)s*5120 + idx]        = hh;
  ps2[(size_t)s*5120 + 2560 + idx] = f2bf(bv - bf2f(hh));
  if (threadIdx.x == 0) rr_arr[s] = rr0;
}

// ---------------- matvec: Ap_part[kh][s][r] via split-bf16 MFMA ----------------
// grid (160 row-blocks of 16, 4 K-quarters), 256 thr (4 waves, wave = 160-col slice).
__global__ __launch_bounds__(256) void k_matvec(
    const unsigned short* __restrict__ M2, const unsigned short* __restrict__ p2,
    float* __restrict__ Ap_part)
{
  __shared__ float red[4][16][33];
  const int tid = threadIdx.x;
  const int w = tid >> 6, l = tid & 63;
  const int ln = l & 15, kq = l >> 4;
  const int R0 = blockIdx.x << 4;
  const int kh = blockIdx.y;                 // 0..3
  const int c0 = kh*640 + w*160;

  const unsigned short* a0p = M2 + (size_t)(R0 + ln)*5120 + c0 + kq*8;
  const unsigned short* q0  = p2 + (size_t)ln*5120        + c0 + kq*8;
  const unsigned short* q1  = p2 + (size_t)(16 + ln)*5120 + c0 + kq*8;

  f32x4 acc[2];
  acc[0] = (f32x4){0.f,0.f,0.f,0.f};
  acc[1] = (f32x4){0.f,0.f,0.f,0.f};

  #pragma unroll
  for (int ch = 0; ch < 5; ch++){
    const int o = ch * 32;
    s16x8 bh0 = *(const s16x8*)(q0 + o);
    s16x8 bl0 = *(const s16x8*)(q0 + 2560 + o);
    s16x8 bh1 = *(const s16x8*)(q1 + o);
    s16x8 bl1 = *(const s16x8*)(q1 + 2560 + o);
    s16x8 a0h = *(const s16x8*)(a0p + o);
    s16x8 a0l = *(const s16x8*)(a0p + 2560 + o);
    acc[0] = __builtin_amdgcn_mfma_f32_16x16x32_bf16(a0h, bh0, acc[0], 0,0,0);
    acc[1] = __builtin_amdgcn_mfma_f32_16x16x32_bf16(a0h, bh1, acc[1], 0,0,0);
    acc[0] = __builtin_amdgcn_mfma_f32_16x16x32_bf16(a0h, bl0, acc[0], 0,0,0);
    acc[1] = __builtin_amdgcn_mfma_f32_16x16x32_bf16(a0h, bl1, acc[1], 0,0,0);
    acc[0] = __builtin_amdgcn_mfma_f32_16x16x32_bf16(a0l, bh0, acc[0], 0,0,0);
    acc[1] = __builtin_amdgcn_mfma_f32_16x16x32_bf16(a0l, bh1, acc[1], 0,0,0);
  }

  #pragma unroll
  for (int g = 0; g < 2; g++)
    #pragma unroll
    for (int q = 0; q < 4; q++)
      red[w][kq*4 + q][16*g + ln] = acc[g][q];
  __syncthreads();
  #pragma unroll
  for (int j = 0; j < 2; j++){
    const int idx = tid + (j << 8);
    const int r = idx & 15, s = idx >> 4;
    float v = red[0][r][s] + red[1][r][s] + red[2][r][s] + red[3][r][s];
    Ap_part[((size_t)kh*NS + s)*NIDX + R0 + r] = v;
  }
}

// ---------------- fused CG update (pAp, alpha, a/r, reortho, beta, p, basis, ps2) ----------------
// 32 blocks x 512 thr (8 waves); thread owns idx = tid + 512c, c<5
__global__ __launch_bounds__(512) void k_cg(
    const float* __restrict__ Ap_part, float* __restrict__ rr_arr, int k, int last,
    float* __restrict__ pv, unsigned short* __restrict__ ps2,
    unsigned short* __restrict__ as2,
    float* __restrict__ av, float* __restrict__ rv, float* __restrict__ basis)
{
  __shared__ float wl[8];
  __shared__ float red[8][10];
  __shared__ float cbr[10];
  const int s = blockIdx.x, tid = threadIdx.x;
  const int w = tid >> 6;
  const size_t base = (size_t)s * NIDX;
  const float rr = rr_arr[s];

  float ap[5], pvv[5];
  #pragma unroll
  for (int c = 0; c < 5; c++){
    const int idx = tid + (c << 9);
    float apv = 0.f;
    #pragma unroll
    for (int kc = 0; kc < 4; kc++)
      apv += Ap_part[((size_t)kc*NS + s)*NIDX + idx];
    ap[c]  = apv;
    pvv[c] = pv[base + idx];
  }
  float v = 0.f;
  #pragma unroll
  for (int c = 0; c < 5; c++) v += pvv[c] * ap[c];
  v = wave_red(v);
  if ((tid & 63) == 0) wl[w] = v;
  __syncthreads();
  const float pAp = wl[0]+wl[1]+wl[2]+wl[3]+wl[4]+wl[5]+wl[6]+wl[7];
  const float alpha = rr / (pAp + CG_EPS);

  float rn[5];
  #pragma unroll
  for (int c = 0; c < 5; c++){
    const int idx = tid + (c << 9);
    const float an = av[base + idx] + alpha * pvv[c];
    av[base + idx] = an;
    rn[c] = rv[base + idx] - alpha * ap[c];
    if (last){
      unsigned short hh = f2bf(an);
      as2[(size_t)s*5120 + idx]        = hh;
      as2[(size_t)s*5120 + 2560 + idx] = f2bf(an - bf2f(hh));
    }
  }

  for (int j = 0; j <= k; j++){
    float cv = 0.f;
    const float* brow = basis + (size_t)j * (NS*NIDX) + base;
    #pragma unroll
    for (int c = 0; c < 5; c++) cv += brow[tid + (c << 9)] * rn[c];
    cv = wave_red(cv);
    if ((tid & 63) == 0) red[w][j] = cv;
  }
  __syncthreads();
  if (tid <= k){
    float cs = 0.f;
    #pragma unroll
    for (int ww = 0; ww < 8; ww++) cs += red[ww][tid];
    cbr[tid] = cs;
  }
  __syncthreads();

  for (int j = 0; j <= k; j++){
    const float cc = cbr[j];
    const float* brow = basis + (size_t)j * (NS*NIDX) + base;
    #pragma unroll
    for (int c = 0; c < 5; c++) rn[c] -= brow[tid + (c << 9)] * cc;
  }

  float rr2 = 0.f;
  #pragma unroll
  for (int c = 0; c < 5; c++) rr2 += rn[c]*rn[c];
  rr2 = wave_red(rr2);
  __syncthreads();
  if ((tid & 63) == 0) wl[w] = rr2;
  __syncthreads();
  const float rrn = wl[0]+wl[1]+wl[2]+wl[3]+wl[4]+wl[5]+wl[6]+wl[7];
  const float beta = rrn / (rr + CG_EPS);
  const float inv  = 1.0f / (sqrtf(rrn) + CG_EPS);

  float* bnew = basis + (size_t)(k+1) * (NS*NIDX) + base;
  #pragma unroll
  for (int c = 0; c < 5; c++){
    const int idx = tid + (c << 9);
    const float pnew = rn[c] + beta * pvv[c];
    rv[base + idx] = rn[c];
    pv[base + idx] = pnew;
    bnew[idx] = rn[c] * inv;
    unsigned short hh = f2bf(pnew);
    ps2[(size_t)s*5120 + idx]        = hh;
    ps2[(size_t)s*5120 + 2560 + idx] = f2bf(pnew - bf2f(hh));
  }
  if (tid == 0) rr_arr[s] = rrn;
}

// ---------------- final: preds = out0 + si*b + (sk-si)*(M a) ----------------
__global__ __launch_bounds__(256) void k_final(
    const float* __restrict__ out0, const float* __restrict__ bvec,
    const float* __restrict__ Ap_part, const float* __restrict__ lp,
    const float* __restrict__ lsi, float* __restrict__ out)
{
  int gid = blockIdx.x * 256 + threadIdx.x;
  int s = gid / NIDX, idx = gid - s * NIDX;
  float sk = expf(-0.5f * lp[0]);
  float si = expf(lsi[0]);
  float ma = 0.f;
  #pragma unroll
  for (int kc = 0; kc < 4; kc++) ma += Ap_part[(size_t)kc*NS*NIDX + gid];
  out[gid] = out0[idx] + si * bvec[gid] + (sk - si) * ma;
}

// ---------------- launch ----------------
extern "C" void kernel_launch(void* const* d_in, const int* in_sizes, int n_in,
                              void* d_out, int out_size, void* d_ws, size_t ws_size,
                              hipStream_t stream)
{
  const float* x   = (const float*)d_in[0];
  const float* W1  = (const float*)d_in[1];
  const float* b1  = (const float*)d_in[2];
  const float* W2  = (const float*)d_in[3];
  const float* b2  = (const float*)d_in[4];
  const float* eW1 = (const float*)d_in[5];
  const float* eb1 = (const float*)d_in[6];
  const float* eW2 = (const float*)d_in[7];
  const float* eb2 = (const float*)d_in[8];
  const float* lp  = (const float*)d_in[9];
  const float* lsi = (const float*)d_in[10];
  float* outp = (float*)d_out;

  float* ws = (float*)d_ws;
  float* h        = ws;                       // 131072
  float* G        = h        + 131072;        // 131072
  float* Kx       = G        + 131072;        // 65536
  float* Kh       = Kx       + 65536;         // 65536
  float* E2f      = Kh       + 65536;         // 1310720 (2560x1024 bf16 hi|lo)
  float* x2f      = E2f      + 1310720;       // 131072  (256x1024 bf16 hi|lo)
  float* M2f      = x2f      + 131072;        // 6553600 (2560x5120 bf16 hi|lo); T aliases
  float* out0     = M2f      + 6553600;       // 2560
  float* bvec     = out0     + 2560;          // 81920
  float* rv       = bvec     + 81920;         // 81920
  float* pv       = rv       + 81920;         // 81920
  float* av       = pv       + 81920;         // 81920
  float* basis    = av       + 81920;         // 901120 (11*81920); Kp aliases head
  float* Ap_part  = basis    + 901120;        // 327680 (4*32*2560); h2 aliases head
  float* ps2f     = Ap_part  + 327680;        // 81920 floats (32x5120 ushorts hi|lo)
  float* as2f     = ps2f     + 81920;         // 81920 floats
  float* rr0_part = as2f     + 81920;         // 320
  float* rr_arr   = rr0_part + 320;           // 32
  // total ~10.11M floats = ~40.4 MB

  unsigned short* E2  = (unsigned short*)E2f;
  unsigned short* x2  = (unsigned short*)x2f;
  unsigned short* M2  = (unsigned short*)M2f;
  unsigned short* ps2 = (unsigned short*)ps2f;
  unsigned short* as2 = (unsigned short*)as2f;
  float* T  = M2f;                            // alias: T dead before M2 is built
  float* Kp = basis;                          // alias: Kp (524288) dead before k_init
  unsigned short* h2 = (unsigned short*)Ap_part;  // alias: h2 (131072 f) dead before loop

  k_buildx <<<128,          256, 0, stream>>>(x, x2);
  k_gemm_T <<<dim3(8,33),   512, 0, stream>>>(x2, eW1, eb1, W1, b1, T, h, G, h2);
  k_buildE <<<1280,         256, 0, stream>>>(G, W2, E2);
  k_kxkh   <<<dim3(4,4,8),  256, 0, stream>>>(x, h, Kp);
  k_comb   <<<512,          256, 0, stream>>>(Kp, Kx, Kh);
  k_bvec   <<<320,          256, 0, stream>>>(T, W2, h, G, eW2, eb2, b2, bvec, out0, rr0_part);
  k_gemm_M <<<dim3(40,20),  256, 0, stream>>>(E2, Kx, Kh, M2);  // overwrites T (dead)
  k_init   <<<320,          256, 0, stream>>>(bvec, rr0_part, rv, pv, av, basis, rr_arr, ps2);

  for (int k = 0; k < MAXIT; k++){
    k_matvec<<<dim3(160,4), 256, 0, stream>>>(M2, ps2, Ap_part);
    k_cg    <<<NS,          512, 0, stream>>>(Ap_part, rr_arr, k, (k == MAXIT-1),
                                              pv, ps2, as2, av, rv, basis);
  }

  k_matvec<<<dim3(160,4), 256, 0, stream>>>(M2, as2, Ap_part);
  k_final <<<320,         256, 0, stream>>>(out0, bvec, Ap_part, lp, lsi, outp);
}